// Round 1
// baseline (4957.539 us; speedup 1.0000x reference)
//
#include <hip/hip_runtime.h>

#define NAPP  100000
#define NATTR 50000
#define NE    500000
#define D     128

// ---------------- degree: deg[dst[e]] += 1 ----------------
__global__ __launch_bounds__(256) void deg_kernel(const int* __restrict__ dst,
                                                  float* __restrict__ deg, int ne) {
    int i = blockIdx.x * 256 + threadIdx.x;
    if (i < ne) unsafeAtomicAdd(&deg[dst[i]], 1.0f);
}

// ---------------- edge aggregation: agg[dst] += ew * x[src] ----------------
// 32 lanes per edge, float4 per lane (512B/edge), 4 f32 HW atomics per lane.
__global__ __launch_bounds__(256) void edge_agg_kernel(const float* __restrict__ x,
        const int* __restrict__ src, const int* __restrict__ dst,
        const float* __restrict__ ew, float* __restrict__ agg, int ne) {
    int e = (blockIdx.x * 256 + threadIdx.x) >> 5;
    int lane = threadIdx.x & 31;
    if (e >= ne) return;
    int s = src[e];
    int d = dst[e];
    float w = ew[e];
    float4 v = *((const float4*)(x + (size_t)s * D) + lane);
    float* ap = agg + (size_t)d * D + lane * 4;
    unsafeAtomicAdd(ap + 0, v.x * w);
    unsafeAtomicAdd(ap + 1, v.y * w);
    unsafeAtomicAdd(ap + 2, v.z * w);
    unsafeAtomicAdd(ap + 3, v.w * w);
}

// ---------------- combine self-weights/biases for 'app' dst ----------------
__global__ __launch_bounds__(256) void prep_kernel(
        const float* __restrict__ Wself1, const float* __restrict__ b1,
        const float* __restrict__ Wself2, const float* __restrict__ b2,
        float* __restrict__ W1s, float* __restrict__ b1s,
        float* __restrict__ W2s, float* __restrict__ b2s) {
    int i = blockIdx.x * 256 + threadIdx.x;
    if (i < D * D) {
        W1s[i] = Wself1[D * D + i] + Wself1[2 * D * D + i];
        W2s[i] = Wself2[D * D + i] + Wself2[2 * D * D + i];
    }
    if (i < D) {
        b1s[i] = b1[D + i] + b1[2 * D + i];
        b2s[i] = b2[D + i] + b2[2 * D + i];
    }
}

// ---------------- fused node update ----------------
// out[r][:] = act( in0[r]@W0 + norm(in1,dg1)[r]@W1 (+ norm(in2,dg2)[r]@W2) + bias )
// 64 rows/block; thread = 8 rows x 4 cols (32 f32 acc). LDS tile row-major,
// stride 132 (conflict-free writes, 16B-aligned b128 reads, rg pairs 2-way=free).
template<int NS>
__global__ __launch_bounds__(256) void node_gemm_kernel(
        const float* __restrict__ in0, const float* __restrict__ W0,
        const float* __restrict__ in1, const float* __restrict__ dg1, const float* __restrict__ W1,
        const float* __restrict__ in2, const float* __restrict__ dg2, const float* __restrict__ W2,
        const float* __restrict__ bias, float* __restrict__ out,
        int nrows, int dorelu) {
    __shared__ float tile[64 * 132];
    const int t = threadIdx.x;
    const int row0 = blockIdx.x * 64;
    const int ct = t & 31;   // cols 4*ct .. 4*ct+3
    const int rg = t >> 5;   // rows 8*rg .. 8*rg+7

    float4 acc[8];
    #pragma unroll
    for (int i = 0; i < 8; i++) acc[i] = make_float4(0.f, 0.f, 0.f, 0.f);

    const float* ins[3] = { in0, in1, in2 };
    const float* dgs[3] = { nullptr, dg1, dg2 };
    const float* Wm[3]  = { W0, W1, W2 };

    #pragma unroll
    for (int s = 0; s < NS; s++) {
        const float* __restrict__ in = ins[s];
        const float* __restrict__ dg = dgs[s];
        const float* __restrict__ W  = Wm[s];
        __syncthreads();
        // stage 64x128 tile, transposed-normalized on the fly
        #pragma unroll 8
        for (int p = 0; p < 32; p++) {
            int id = p * 256 + t;
            int k = id & 127;
            int r = id >> 7;
            int row = row0 + r;
            float v = 0.f;
            if (row < nrows) {
                v = in[(size_t)row * D + k];
                if (dg != nullptr) v *= 1.0f / fmaxf(dg[row], 1.0f);
            }
            tile[r * 132 + k] = v;
        }
        __syncthreads();
        for (int k4 = 0; k4 < 32; k4++) {
            const float* wrow = W + k4 * 4 * D + ct * 4;
            float4 w0 = *(const float4*)(wrow);
            float4 w1 = *(const float4*)(wrow + D);
            float4 w2 = *(const float4*)(wrow + 2 * D);
            float4 w3 = *(const float4*)(wrow + 3 * D);
            #pragma unroll
            for (int i = 0; i < 8; i++) {
                float4 xv = *(const float4*)&tile[(rg * 8 + i) * 132 + k4 * 4];
                acc[i].x += xv.x * w0.x + xv.y * w1.x + xv.z * w2.x + xv.w * w3.x;
                acc[i].y += xv.x * w0.y + xv.y * w1.y + xv.z * w2.y + xv.w * w3.y;
                acc[i].z += xv.x * w0.z + xv.y * w1.z + xv.z * w2.z + xv.w * w3.z;
                acc[i].w += xv.x * w0.w + xv.y * w1.w + xv.z * w2.w + xv.w * w3.w;
            }
        }
    }

    float4 bv = *(const float4*)(bias + ct * 4);
    #pragma unroll
    for (int i = 0; i < 8; i++) {
        int row = row0 + rg * 8 + i;
        if (row < nrows) {
            float4 o = acc[i];
            o.x += bv.x; o.y += bv.y; o.z += bv.z; o.w += bv.w;
            if (dorelu) {
                o.x = fmaxf(o.x, 0.f); o.y = fmaxf(o.y, 0.f);
                o.z = fmaxf(o.z, 0.f); o.w = fmaxf(o.w, 0.f);
            }
            *(float4*)(out + (size_t)row * D + ct * 4) = o;
        }
    }
}

// ---------------- classifier: out[r] = h[r] @ Wc + bc ----------------
__global__ __launch_bounds__(256) void classify_kernel(
        const float* __restrict__ h, const float* __restrict__ Wc,
        const float* __restrict__ bc, float* __restrict__ out, int nrows) {
    int w = (blockIdx.x * 256 + threadIdx.x) >> 6;
    int lane = threadIdx.x & 63;
    if (w >= nrows) return;
    float2 v = *(const float2*)(h + (size_t)w * D + lane * 2);
    float4 wc = *(const float4*)(Wc + lane * 4); // Wc[2l][0..1], Wc[2l+1][0..1]
    float p0 = v.x * wc.x + v.y * wc.z;
    float p1 = v.x * wc.y + v.y * wc.w;
    #pragma unroll
    for (int off = 32; off > 0; off >>= 1) {
        p0 += __shfl_down(p0, off);
        p1 += __shfl_down(p1, off);
    }
    if (lane == 0) {
        out[(size_t)w * 2 + 0] = p0 + bc[0];
        out[(size_t)w * 2 + 1] = p1 + bc[1];
    }
}

extern "C" void kernel_launch(void* const* d_in, const int* in_sizes, int n_in,
                              void* d_out, int out_size, void* d_ws, size_t ws_size,
                              hipStream_t stream) {
    const float* x_app   = (const float*)d_in[0];
    const float* x_attr  = (const float*)d_in[1];
    const float* ew0     = (const float*)d_in[2];
    const float* ew1     = (const float*)d_in[3];
    const float* ew2     = (const float*)d_in[4];
    const float* Wself1  = (const float*)d_in[5];
    const float* Wneigh1 = (const float*)d_in[6];
    const float* b1      = (const float*)d_in[7];
    const float* Wself2  = (const float*)d_in[8];
    const float* Wneigh2 = (const float*)d_in[9];
    const float* b2      = (const float*)d_in[10];
    const float* Wc      = (const float*)d_in[11];
    const float* bc      = (const float*)d_in[12];
    const int* src0 = (const int*)d_in[13];
    const int* dst0 = (const int*)d_in[14];
    const int* src1 = (const int*)d_in[15];
    const int* dst1 = (const int*)d_in[16];
    const int* src2 = (const int*)d_in[17];
    const int* dst2 = (const int*)d_in[18];
    float* out = (float*)d_out;

    // workspace layout (floats), ~206 MB total
    float* ws = (float*)d_ws;
    float* agg0   = ws;                                  // NATTR*D
    float* h_attr = agg0   + (size_t)NATTR * D;          // NATTR*D
    float* agg1   = h_attr + (size_t)NATTR * D;          // NAPP*D
    float* agg2   = agg1   + (size_t)NAPP * D;           // NAPP*D
    float* h_app  = agg2   + (size_t)NAPP * D;           // NAPP*D
    float* deg0   = h_app  + (size_t)NAPP * D;           // NATTR
    float* deg1   = deg0 + NATTR;                        // NAPP
    float* deg2   = deg1 + NAPP;                         // NAPP
    float* W1s    = deg2 + NAPP;                         // D*D
    float* W2s    = W1s + D * D;                         // D*D
    float* b1s    = W2s + D * D;                         // D
    float* b2s    = b1s + D;                             // D
    float* h_app2 = agg0;  // reuse agg0+h_attr (both dead by layer-2 GEMM)

    // zero accumulators & degrees
    hipMemsetAsync(agg0, 0, (size_t)NATTR * D * sizeof(float), stream);
    hipMemsetAsync(agg1, 0, (size_t)2 * NAPP * D * sizeof(float), stream);
    hipMemsetAsync(deg0, 0, (size_t)(NATTR + 2 * NAPP) * sizeof(float), stream);

    prep_kernel<<<(D * D + 255) / 256, 256, 0, stream>>>(Wself1, b1, Wself2, b2,
                                                         W1s, b1s, W2s, b2s);

    deg_kernel<<<(NE + 255) / 256, 256, 0, stream>>>(dst0, deg0, NE);
    deg_kernel<<<(NE + 255) / 256, 256, 0, stream>>>(dst1, deg1, NE);
    deg_kernel<<<(NE + 255) / 256, 256, 0, stream>>>(dst2, deg2, NE);

    const int eb = (NE * 32 + 255) / 256;  // 62500 blocks, 8 edges/block
    // layer 1 aggregations
    edge_agg_kernel<<<eb, 256, 0, stream>>>(x_app,  src0, dst0, ew0, agg0, NE);
    edge_agg_kernel<<<eb, 256, 0, stream>>>(x_attr, src1, dst1, ew1, agg1, NE);
    edge_agg_kernel<<<eb, 256, 0, stream>>>(x_app,  src2, dst2, ew2, agg2, NE);

    // layer 1 node updates
    node_gemm_kernel<2><<<(NATTR + 63) / 64, 256, 0, stream>>>(
        x_attr, Wself1, agg0, deg0, Wneigh1,
        nullptr, nullptr, nullptr, b1, h_attr, NATTR, 1);
    node_gemm_kernel<3><<<(NAPP + 63) / 64, 256, 0, stream>>>(
        x_app, W1s, agg1, deg1, Wneigh1 + D * D,
        agg2, deg2, Wneigh1 + 2 * D * D, b1s, h_app, NAPP, 1);

    // layer 2 (h_attr2 is unused by the reference -> skip rel0 entirely)
    hipMemsetAsync(agg1, 0, (size_t)2 * NAPP * D * sizeof(float), stream);
    edge_agg_kernel<<<eb, 256, 0, stream>>>(h_attr, src1, dst1, ew1, agg1, NE);
    edge_agg_kernel<<<eb, 256, 0, stream>>>(h_app,  src2, dst2, ew2, agg2, NE);

    node_gemm_kernel<3><<<(NAPP + 63) / 64, 256, 0, stream>>>(
        h_app, W2s, agg1, deg1, Wneigh2 + D * D,
        agg2, deg2, Wneigh2 + 2 * D * D, b2s, h_app2, NAPP, 0);

    classify_kernel<<<(NAPP * 64 + 255) / 256, 256, 0, stream>>>(h_app2, Wc, bc, out, NAPP);
}

// Round 2
// 1332.957 us; speedup vs baseline: 3.7192x; 3.7192x over previous
//
#include <hip/hip_runtime.h>

#define NAPP  100000
#define NATTR 50000
#define NE    500000
#define D     128

// ---------------- histogram: hist[dst[e]] += 1 (int atomics) ----------------
__global__ __launch_bounds__(256) void hist_kernel(const int* __restrict__ dst,
                                                   int* __restrict__ hist, int ne) {
    int i = blockIdx.x * 256 + threadIdx.x;
    if (i < ne) atomicAdd(&hist[dst[i]], 1);
}

// ---------------- per-relation exclusive scan (1 block per relation) --------
// In: hist (in cursor array). Out: cursor[i]=rowptr[i]=exclusive prefix,
// rowptr[n]=total. 256 threads, serial chunks + Hillis-Steele over partials.
__global__ __launch_bounds__(256) void scan_kernel(
        int* __restrict__ cur0, int* __restrict__ rp0,
        int* __restrict__ cur1, int* __restrict__ rp1,
        int* __restrict__ cur2, int* __restrict__ rp2) {
    int* cur; int* rp; int n;
    if (blockIdx.x == 0)      { cur = cur0; rp = rp0; n = NATTR; }
    else if (blockIdx.x == 1) { cur = cur1; rp = rp1; n = NAPP; }
    else                      { cur = cur2; rp = rp2; n = NAPP; }
    const int t = threadIdx.x;
    const int chunk = (n + 255) / 256;
    const int i0 = t * chunk;
    const int i1 = min(i0 + chunk, n);

    int t_sum = 0;
    for (int i = i0; i < i1; i++) t_sum += cur[i];

    __shared__ int sdata[256];
    sdata[t] = t_sum;
    __syncthreads();
    for (int off = 1; off < 256; off <<= 1) {
        int v = (t >= off) ? sdata[t - off] : 0;
        __syncthreads();
        sdata[t] += v;
        __syncthreads();
    }
    int base = sdata[t] - t_sum;     // exclusive prefix of this thread's chunk
    int total = sdata[255];

    int running = base;
    for (int i = i0; i < i1; i++) {
        int c = cur[i];
        rp[i] = running;
        cur[i] = running;
        running += c;
    }
    if (t == 0) rp[n] = total;
}

// ---------------- scatter edges into CSR ----------------
__global__ __launch_bounds__(256) void scatter_kernel(
        const int* __restrict__ src, const int* __restrict__ dst,
        const float* __restrict__ ew, int* __restrict__ cursor,
        int* __restrict__ col, float* __restrict__ wv, int ne) {
    int e = blockIdx.x * 256 + threadIdx.x;
    if (e >= ne) return;
    int p = atomicAdd(&cursor[dst[e]], 1);
    col[p] = src[e];
    wv[p] = ew[e];
}

// ---------------- gather aggregation: agg[d] = (1/max(deg,1)) * sum ew*x[src] ----
// One 64-lane wave per dst row; float2 per lane (512B coalesced row gather).
__global__ __launch_bounds__(256) void gather_kernel(const float* __restrict__ x,
        const int* __restrict__ rowptr, const int* __restrict__ col,
        const float* __restrict__ wv, float* __restrict__ agg, int n) {
    int d = (blockIdx.x * 256 + threadIdx.x) >> 6;
    int lane = threadIdx.x & 63;
    if (d >= n) return;
    int s0 = rowptr[d];
    int s1 = rowptr[d + 1];
    float ax = 0.f, ay = 0.f;
    for (int j = s0; j < s1; j++) {
        int s = col[j];
        float w = wv[j];
        float2 v = *(const float2*)(x + (size_t)s * D + lane * 2);
        ax += w * v.x;
        ay += w * v.y;
    }
    float inv = 1.0f / (float)max(s1 - s0, 1);
    *(float2*)(agg + (size_t)d * D + lane * 2) = make_float2(ax * inv, ay * inv);
}

// ---------------- combine self-weights/biases for 'app' dst ----------------
__global__ __launch_bounds__(256) void prep_kernel(
        const float* __restrict__ Wself1, const float* __restrict__ b1,
        const float* __restrict__ Wself2, const float* __restrict__ b2,
        float* __restrict__ W1s, float* __restrict__ b1s,
        float* __restrict__ W2s, float* __restrict__ b2s) {
    int i = blockIdx.x * 256 + threadIdx.x;
    if (i < D * D) {
        W1s[i] = Wself1[D * D + i] + Wself1[2 * D * D + i];
        W2s[i] = Wself2[D * D + i] + Wself2[2 * D * D + i];
    }
    if (i < D) {
        b1s[i] = b1[D + i] + b1[2 * D + i];
        b2s[i] = b2[D + i] + b2[2 * D + i];
    }
}

// ---------------- fused node update ----------------
// out[r][:] = act( in0[r]@W0 + in1[r]@W1 (+ in2[r]@W2) + bias )
// (agg inputs are pre-normalized by the gather kernel)
template<int NS>
__global__ __launch_bounds__(256) void node_gemm_kernel(
        const float* __restrict__ in0, const float* __restrict__ W0,
        const float* __restrict__ in1, const float* __restrict__ W1,
        const float* __restrict__ in2, const float* __restrict__ W2,
        const float* __restrict__ bias, float* __restrict__ out,
        int nrows, int dorelu) {
    __shared__ float tile[64 * 132];
    const int t = threadIdx.x;
    const int row0 = blockIdx.x * 64;
    const int ct = t & 31;   // cols 4*ct .. 4*ct+3
    const int rg = t >> 5;   // rows 8*rg .. 8*rg+7

    float4 acc[8];
    #pragma unroll
    for (int i = 0; i < 8; i++) acc[i] = make_float4(0.f, 0.f, 0.f, 0.f);

    const float* ins[3] = { in0, in1, in2 };
    const float* Wm[3]  = { W0, W1, W2 };

    #pragma unroll
    for (int s = 0; s < NS; s++) {
        const float* __restrict__ in = ins[s];
        const float* __restrict__ W  = Wm[s];
        __syncthreads();
        #pragma unroll 8
        for (int p = 0; p < 32; p++) {
            int id = p * 256 + t;
            int k = id & 127;
            int r = id >> 7;
            int row = row0 + r;
            float v = 0.f;
            if (row < nrows) v = in[(size_t)row * D + k];
            tile[r * 132 + k] = v;
        }
        __syncthreads();
        for (int k4 = 0; k4 < 32; k4++) {
            const float* wrow = W + k4 * 4 * D + ct * 4;
            float4 w0 = *(const float4*)(wrow);
            float4 w1 = *(const float4*)(wrow + D);
            float4 w2 = *(const float4*)(wrow + 2 * D);
            float4 w3 = *(const float4*)(wrow + 3 * D);
            #pragma unroll
            for (int i = 0; i < 8; i++) {
                float4 xv = *(const float4*)&tile[(rg * 8 + i) * 132 + k4 * 4];
                acc[i].x += xv.x * w0.x + xv.y * w1.x + xv.z * w2.x + xv.w * w3.x;
                acc[i].y += xv.x * w0.y + xv.y * w1.y + xv.z * w2.y + xv.w * w3.y;
                acc[i].z += xv.x * w0.z + xv.y * w1.z + xv.z * w2.z + xv.w * w3.z;
                acc[i].w += xv.x * w0.w + xv.y * w1.w + xv.z * w2.w + xv.w * w3.w;
            }
        }
    }

    float4 bv = *(const float4*)(bias + ct * 4);
    #pragma unroll
    for (int i = 0; i < 8; i++) {
        int row = row0 + rg * 8 + i;
        if (row < nrows) {
            float4 o = acc[i];
            o.x += bv.x; o.y += bv.y; o.z += bv.z; o.w += bv.w;
            if (dorelu) {
                o.x = fmaxf(o.x, 0.f); o.y = fmaxf(o.y, 0.f);
                o.z = fmaxf(o.z, 0.f); o.w = fmaxf(o.w, 0.f);
            }
            *(float4*)(out + (size_t)row * D + ct * 4) = o;
        }
    }
}

// ---------------- classifier: out[r] = h[r] @ Wc + bc ----------------
__global__ __launch_bounds__(256) void classify_kernel(
        const float* __restrict__ h, const float* __restrict__ Wc,
        const float* __restrict__ bc, float* __restrict__ out, int nrows) {
    int w = (blockIdx.x * 256 + threadIdx.x) >> 6;
    int lane = threadIdx.x & 63;
    if (w >= nrows) return;
    float2 v = *(const float2*)(h + (size_t)w * D + lane * 2);
    float4 wc = *(const float4*)(Wc + lane * 4);
    float p0 = v.x * wc.x + v.y * wc.z;
    float p1 = v.x * wc.y + v.y * wc.w;
    #pragma unroll
    for (int off = 32; off > 0; off >>= 1) {
        p0 += __shfl_down(p0, off);
        p1 += __shfl_down(p1, off);
    }
    if (lane == 0) {
        out[(size_t)w * 2 + 0] = p0 + bc[0];
        out[(size_t)w * 2 + 1] = p1 + bc[1];
    }
}

extern "C" void kernel_launch(void* const* d_in, const int* in_sizes, int n_in,
                              void* d_out, int out_size, void* d_ws, size_t ws_size,
                              hipStream_t stream) {
    const float* x_app   = (const float*)d_in[0];
    const float* x_attr  = (const float*)d_in[1];
    const float* ew0     = (const float*)d_in[2];
    const float* ew1     = (const float*)d_in[3];
    const float* ew2     = (const float*)d_in[4];
    const float* Wself1  = (const float*)d_in[5];
    const float* Wneigh1 = (const float*)d_in[6];
    const float* b1      = (const float*)d_in[7];
    const float* Wself2  = (const float*)d_in[8];
    const float* Wneigh2 = (const float*)d_in[9];
    const float* b2      = (const float*)d_in[10];
    const float* Wc      = (const float*)d_in[11];
    const float* bc      = (const float*)d_in[12];
    const int* src0 = (const int*)d_in[13];
    const int* dst0 = (const int*)d_in[14];
    const int* src1 = (const int*)d_in[15];
    const int* dst1 = (const int*)d_in[16];
    const int* src2 = (const int*)d_in[17];
    const int* dst2 = (const int*)d_in[18];
    float* out = (float*)d_out;

    // ---- workspace layout (4-byte units), ~230 MB total ----
    float* ws = (float*)d_ws;
    float* agg0   = ws;                                  // NATTR*D
    float* h_attr = agg0   + (size_t)NATTR * D;          // NATTR*D
    float* agg1   = h_attr + (size_t)NATTR * D;          // NAPP*D
    float* agg2   = agg1   + (size_t)NAPP * D;           // NAPP*D
    float* h_app  = agg2   + (size_t)NAPP * D;           // NAPP*D
    float* W1s    = h_app  + (size_t)NAPP * D;           // D*D
    float* W2s    = W1s + D * D;                         // D*D
    float* b1s    = W2s + D * D;                         // D
    float* b2s    = b1s + D;                             // D
    int* cur0 = (int*)(b2s + D);                         // NATTR (hist->cursor)
    int* cur1 = cur0 + NATTR;                            // NAPP
    int* cur2 = cur1 + NAPP;                             // NAPP
    int* rp0  = cur2 + NAPP;                             // NATTR+1
    int* rp1  = rp0 + NATTR + 1;                         // NAPP+1
    int* rp2  = rp1 + NAPP + 1;                          // NAPP+1
    int* col0 = rp2 + NAPP + 1;                          // E
    float* wv0 = (float*)(col0 + NE);                    // E
    int* col1 = (int*)(wv0 + NE);                        // E
    float* wv1 = (float*)(col1 + NE);                    // E
    int* col2 = (int*)(wv1 + NE);                        // E
    float* wv2 = (float*)(col2 + NE);                    // E
    float* h_app2 = agg0;  // reuse (agg0 dead after layer-1 attr GEMM)

    // zero histograms (cursor region is contiguous)
    hipMemsetAsync(cur0, 0, (size_t)(NATTR + 2 * NAPP) * sizeof(int), stream);

    prep_kernel<<<(D * D + 255) / 256, 256, 0, stream>>>(Wself1, b1, Wself2, b2,
                                                         W1s, b1s, W2s, b2s);

    const int egrid = (NE + 255) / 256;
    // ---- CSR build (once; rel1/rel2 reused by both layers) ----
    hist_kernel<<<egrid, 256, 0, stream>>>(dst0, cur0, NE);
    hist_kernel<<<egrid, 256, 0, stream>>>(dst1, cur1, NE);
    hist_kernel<<<egrid, 256, 0, stream>>>(dst2, cur2, NE);
    scan_kernel<<<3, 256, 0, stream>>>(cur0, rp0, cur1, rp1, cur2, rp2);
    scatter_kernel<<<egrid, 256, 0, stream>>>(src0, dst0, ew0, cur0, col0, wv0, NE);
    scatter_kernel<<<egrid, 256, 0, stream>>>(src1, dst1, ew1, cur1, col1, wv1, NE);
    scatter_kernel<<<egrid, 256, 0, stream>>>(src2, dst2, ew2, cur2, col2, wv2, NE);

    // ---- layer 1 aggregations (gather, normalized) ----
    gather_kernel<<<((size_t)NATTR * 64 + 255) / 256, 256, 0, stream>>>(x_app,  rp0, col0, wv0, agg0, NATTR);
    gather_kernel<<<((size_t)NAPP * 64 + 255) / 256, 256, 0, stream>>>(x_attr, rp1, col1, wv1, agg1, NAPP);
    gather_kernel<<<((size_t)NAPP * 64 + 255) / 256, 256, 0, stream>>>(x_app,  rp2, col2, wv2, agg2, NAPP);

    // ---- layer 1 node updates ----
    node_gemm_kernel<2><<<(NATTR + 63) / 64, 256, 0, stream>>>(
        x_attr, Wself1, agg0, Wneigh1, nullptr, nullptr, b1, h_attr, NATTR, 1);
    node_gemm_kernel<3><<<(NAPP + 63) / 64, 256, 0, stream>>>(
        x_app, W1s, agg1, Wneigh1 + D * D, agg2, Wneigh1 + 2 * D * D,
        b1s, h_app, NAPP, 1);

    // ---- layer 2 (attr output unused by classify -> skip rel0) ----
    gather_kernel<<<((size_t)NAPP * 64 + 255) / 256, 256, 0, stream>>>(h_attr, rp1, col1, wv1, agg1, NAPP);
    gather_kernel<<<((size_t)NAPP * 64 + 255) / 256, 256, 0, stream>>>(h_app,  rp2, col2, wv2, agg2, NAPP);

    node_gemm_kernel<3><<<(NAPP + 63) / 64, 256, 0, stream>>>(
        h_app, W2s, agg1, Wneigh2 + D * D, agg2, Wneigh2 + 2 * D * D,
        b2s, h_app2, NAPP, 0);

    classify_kernel<<<((size_t)NAPP * 64 + 255) / 256, 256, 0, stream>>>(h_app2, Wc, bc, out, NAPP);
}

// Round 3
// 1055.072 us; speedup vs baseline: 4.6988x; 1.2634x over previous
//
#include <hip/hip_runtime.h>

#define NAPP  100000
#define NATTR 50000
#define NE    500000
#define D     128
#define NTOT  (NATTR + 2 * NAPP)          // 250000 concatenated histogram
#define SCHUNK 1024
#define SNB   ((NTOT + SCHUNK - 1) / SCHUNK)  // 245 scan blocks

// ---------------- histogram: hist[dst[e]] += 1 (int atomics) ----------------
__global__ __launch_bounds__(256) void hist_kernel(const int* __restrict__ dst,
                                                   int* __restrict__ hist, int ne) {
    int i = blockIdx.x * 256 + threadIdx.x;
    if (i < ne) atomicAdd(&hist[dst[i]], 1);
}

// ---------------- scan phase A: per-block partial sums ----------------
__global__ __launch_bounds__(256) void scan_partial_kernel(const int* __restrict__ cur,
                                                           int* __restrict__ bsum) {
    int b = blockIdx.x, t = threadIdx.x;
    int4 v = *((const int4*)(cur + b * SCHUNK) + t);   // tail chunks read memset-0 pad
    int s = v.x + v.y + v.z + v.w;
    __shared__ int sd[256];
    sd[t] = s;
    __syncthreads();
    for (int off = 128; off > 0; off >>= 1) {
        if (t < off) sd[t] += sd[t + off];
        __syncthreads();
    }
    if (t == 0) bsum[b] = sd[0];
}

// ---------------- scan phase B: scan of block sums (1 block) ----------------
__global__ __launch_bounds__(256) void scan_offsets_kernel(const int* __restrict__ bsum,
        int* __restrict__ boff, int* __restrict__ rp0, int* __restrict__ rp1,
        int* __restrict__ rp2) {
    int t = threadIdx.x;
    int v = (t < SNB) ? bsum[t] : 0;
    __shared__ int sd[256];
    sd[t] = v;
    __syncthreads();
    for (int off = 1; off < 256; off <<= 1) {
        int u = (t >= off) ? sd[t - off] : 0;
        __syncthreads();
        sd[t] += u;
        __syncthreads();
    }
    boff[t] = sd[t] - v;   // exclusive
    if (t == 0) { rp0[NATTR] = NE; rp1[NAPP] = NE; rp2[NAPP] = NE; }
}

// ---------------- scan phase C: block-local scan + offset, write rowptr/cursor ----
__global__ __launch_bounds__(256) void scan_final_kernel(int* __restrict__ cur,
        const int* __restrict__ boff, int* __restrict__ rp0, int* __restrict__ rp1,
        int* __restrict__ rp2) {
    int b = blockIdx.x, t = threadIdx.x;
    int base = b * SCHUNK + t * 4;
    int4 v = *(const int4*)(cur + base);
    int s = v.x + v.y + v.z + v.w;
    __shared__ int sd[256];
    sd[t] = s;
    __syncthreads();
    for (int off = 1; off < 256; off <<= 1) {
        int u = (t >= off) ? sd[t - off] : 0;
        __syncthreads();
        sd[t] += u;
        __syncthreads();
    }
    int pre = boff[b] + sd[t] - s;
    int ex[4];
    ex[0] = pre;
    ex[1] = ex[0] + v.x;
    ex[2] = ex[1] + v.y;
    ex[3] = ex[2] + v.z;
    #pragma unroll
    for (int i = 0; i < 4; i++) {
        int idx = base + i;
        if (idx < NTOT) {
            int* rp; int loc; int rbase;
            if (idx < NATTR)             { rp = rp0; loc = idx;                 rbase = 0; }
            else if (idx < NATTR + NAPP) { rp = rp1; loc = idx - NATTR;        rbase = NE; }
            else                         { rp = rp2; loc = idx - NATTR - NAPP; rbase = 2 * NE; }
            int val = ex[i] - rbase;
            rp[loc] = val;
            cur[idx] = val;
        }
    }
}

// ---------------- scatter edges into CSR ----------------
__global__ __launch_bounds__(256) void scatter_kernel(
        const int* __restrict__ src, const int* __restrict__ dst,
        const float* __restrict__ ew, int* __restrict__ cursor,
        int* __restrict__ col, float* __restrict__ wv, int ne) {
    int e = blockIdx.x * 256 + threadIdx.x;
    if (e >= ne) return;
    int p = atomicAdd(&cursor[dst[e]], 1);
    col[p] = src[e];
    wv[p] = ew[e];
}

// ---------------- gather aggregation: agg[d] = (1/max(deg,1)) * sum ew*x[src] ----
// One 64-lane wave per dst row; float2 per lane; index loads software-pipelined.
__global__ __launch_bounds__(256) void gather_kernel(const float* __restrict__ x,
        const int* __restrict__ rowptr, const int* __restrict__ col,
        const float* __restrict__ wv, float* __restrict__ agg, int n) {
    int d = (blockIdx.x * 256 + threadIdx.x) >> 6;
    int lane = threadIdx.x & 63;
    if (d >= n) return;
    int s0 = rowptr[d];
    int s1 = rowptr[d + 1];
    float ax = 0.f, ay = 0.f;
    if (s1 > s0) {
        int s = col[s0];
        float w = wv[s0];
        for (int j = s0 + 1; j < s1; j++) {
            int sn = col[j];       // prefetch next index/weight while row gather
            float wn = wv[j];      // is in flight
            float2 v = *(const float2*)(x + (size_t)s * D + lane * 2);
            ax += w * v.x;
            ay += w * v.y;
            s = sn; w = wn;
        }
        float2 v = *(const float2*)(x + (size_t)s * D + lane * 2);
        ax += w * v.x;
        ay += w * v.y;
    }
    float inv = 1.0f / (float)max(s1 - s0, 1);
    *(float2*)(agg + (size_t)d * D + lane * 2) = make_float2(ax * inv, ay * inv);
}

// ---------------- combine self-weights/biases for 'app' dst ----------------
__global__ __launch_bounds__(256) void prep_kernel(
        const float* __restrict__ Wself1, const float* __restrict__ b1,
        const float* __restrict__ Wself2, const float* __restrict__ b2,
        float* __restrict__ W1s, float* __restrict__ b1s,
        float* __restrict__ W2s, float* __restrict__ b2s) {
    int i = blockIdx.x * 256 + threadIdx.x;
    if (i < D * D) {
        W1s[i] = Wself1[D * D + i] + Wself1[2 * D * D + i];
        W2s[i] = Wself2[D * D + i] + Wself2[2 * D * D + i];
    }
    if (i < D) {
        b1s[i] = b1[D + i] + b1[2 * D + i];
        b2s[i] = b2[D + i] + b2[2 * D + i];
    }
}

// ---------------- fused node update ----------------
// out[r][:] = act( in0[r]@W0 + in1[r]@W1 (+ in2[r]@W2) + bias )
template<int NS>
__global__ __launch_bounds__(256) void node_gemm_kernel(
        const float* __restrict__ in0, const float* __restrict__ W0,
        const float* __restrict__ in1, const float* __restrict__ W1,
        const float* __restrict__ in2, const float* __restrict__ W2,
        const float* __restrict__ bias, float* __restrict__ out,
        int nrows, int dorelu) {
    __shared__ float tile[64 * 132];
    const int t = threadIdx.x;
    const int row0 = blockIdx.x * 64;
    const int ct = t & 31;   // cols 4*ct .. 4*ct+3
    const int rg = t >> 5;   // rows 8*rg .. 8*rg+7

    float4 acc[8];
    #pragma unroll
    for (int i = 0; i < 8; i++) acc[i] = make_float4(0.f, 0.f, 0.f, 0.f);

    const float* ins[3] = { in0, in1, in2 };
    const float* Wm[3]  = { W0, W1, W2 };

    #pragma unroll
    for (int s = 0; s < NS; s++) {
        const float* __restrict__ in = ins[s];
        const float* __restrict__ W  = Wm[s];
        __syncthreads();
        #pragma unroll 8
        for (int p = 0; p < 32; p++) {
            int id = p * 256 + t;
            int k = id & 127;
            int r = id >> 7;
            int row = row0 + r;
            float v = 0.f;
            if (row < nrows) v = in[(size_t)row * D + k];
            tile[r * 132 + k] = v;
        }
        __syncthreads();
        for (int k4 = 0; k4 < 32; k4++) {
            const float* wrow = W + k4 * 4 * D + ct * 4;
            float4 w0 = *(const float4*)(wrow);
            float4 w1 = *(const float4*)(wrow + D);
            float4 w2 = *(const float4*)(wrow + 2 * D);
            float4 w3 = *(const float4*)(wrow + 3 * D);
            #pragma unroll
            for (int i = 0; i < 8; i++) {
                float4 xv = *(const float4*)&tile[(rg * 8 + i) * 132 + k4 * 4];
                acc[i].x += xv.x * w0.x + xv.y * w1.x + xv.z * w2.x + xv.w * w3.x;
                acc[i].y += xv.x * w0.y + xv.y * w1.y + xv.z * w2.y + xv.w * w3.y;
                acc[i].z += xv.x * w0.z + xv.y * w1.z + xv.z * w2.z + xv.w * w3.z;
                acc[i].w += xv.x * w0.w + xv.y * w1.w + xv.z * w2.w + xv.w * w3.w;
            }
        }
    }

    float4 bv = *(const float4*)(bias + ct * 4);
    #pragma unroll
    for (int i = 0; i < 8; i++) {
        int row = row0 + rg * 8 + i;
        if (row < nrows) {
            float4 o = acc[i];
            o.x += bv.x; o.y += bv.y; o.z += bv.z; o.w += bv.w;
            if (dorelu) {
                o.x = fmaxf(o.x, 0.f); o.y = fmaxf(o.y, 0.f);
                o.z = fmaxf(o.z, 0.f); o.w = fmaxf(o.w, 0.f);
            }
            *(float4*)(out + (size_t)row * D + ct * 4) = o;
        }
    }
}

// ---------------- classifier: out[r] = h[r] @ Wc + bc ----------------
__global__ __launch_bounds__(256) void classify_kernel(
        const float* __restrict__ h, const float* __restrict__ Wc,
        const float* __restrict__ bc, float* __restrict__ out, int nrows) {
    int w = (blockIdx.x * 256 + threadIdx.x) >> 6;
    int lane = threadIdx.x & 63;
    if (w >= nrows) return;
    float2 v = *(const float2*)(h + (size_t)w * D + lane * 2);
    float4 wc = *(const float4*)(Wc + lane * 4);
    float p0 = v.x * wc.x + v.y * wc.z;
    float p1 = v.x * wc.y + v.y * wc.w;
    #pragma unroll
    for (int off = 32; off > 0; off >>= 1) {
        p0 += __shfl_down(p0, off);
        p1 += __shfl_down(p1, off);
    }
    if (lane == 0) {
        out[(size_t)w * 2 + 0] = p0 + bc[0];
        out[(size_t)w * 2 + 1] = p1 + bc[1];
    }
}

extern "C" void kernel_launch(void* const* d_in, const int* in_sizes, int n_in,
                              void* d_out, int out_size, void* d_ws, size_t ws_size,
                              hipStream_t stream) {
    const float* x_app   = (const float*)d_in[0];
    const float* x_attr  = (const float*)d_in[1];
    const float* ew0     = (const float*)d_in[2];
    const float* ew1     = (const float*)d_in[3];
    const float* ew2     = (const float*)d_in[4];
    const float* Wself1  = (const float*)d_in[5];
    const float* Wneigh1 = (const float*)d_in[6];
    const float* b1      = (const float*)d_in[7];
    const float* Wself2  = (const float*)d_in[8];
    const float* Wneigh2 = (const float*)d_in[9];
    const float* b2      = (const float*)d_in[10];
    const float* Wc      = (const float*)d_in[11];
    const float* bc      = (const float*)d_in[12];
    const int* src0 = (const int*)d_in[13];
    const int* dst0 = (const int*)d_in[14];
    const int* src1 = (const int*)d_in[15];
    const int* dst1 = (const int*)d_in[16];
    const int* src2 = (const int*)d_in[17];
    const int* dst2 = (const int*)d_in[18];
    float* out = (float*)d_out;

    // ---- workspace layout (4-byte units) ----
    float* ws = (float*)d_ws;
    float* agg0   = ws;                                  // NATTR*D
    float* h_attr = agg0   + (size_t)NATTR * D;          // NATTR*D
    float* agg1   = h_attr + (size_t)NATTR * D;          // NAPP*D
    float* agg2   = agg1   + (size_t)NAPP * D;           // NAPP*D
    float* h_app  = agg2   + (size_t)NAPP * D;           // NAPP*D
    float* W1s    = h_app  + (size_t)NAPP * D;           // D*D
    float* W2s    = W1s + D * D;                         // D*D
    float* b1s    = W2s + D * D;                         // D
    float* b2s    = b1s + D;                             // D
    int* cur  = (int*)(b2s + D);                         // SNB*SCHUNK (padded, 16B-aligned)
    int* cur0 = cur;
    int* cur1 = cur0 + NATTR;
    int* cur2 = cur1 + NAPP;
    int* rp0  = cur + SNB * SCHUNK;                      // NATTR+1 (pad to +4)
    int* rp1  = rp0 + NATTR + 4;                         // NAPP+1
    int* rp2  = rp1 + NAPP + 4;                          // NAPP+1
    int* bsum = rp2 + NAPP + 4;                          // 256
    int* boff = bsum + 256;                              // 256
    int* col0 = boff + 256;                              // E
    float* wv0 = (float*)(col0 + NE);                    // E
    int* col1 = (int*)(wv0 + NE);                        // E
    float* wv1 = (float*)(col1 + NE);                    // E
    int* col2 = (int*)(wv1 + NE);                        // E
    float* wv2 = (float*)(col2 + NE);                    // E
    float* h_app2 = agg0;  // reuse (agg0 dead after layer-1 attr GEMM)

    // zero histogram region incl. scan padding
    hipMemsetAsync(cur, 0, (size_t)SNB * SCHUNK * sizeof(int), stream);

    prep_kernel<<<(D * D + 255) / 256, 256, 0, stream>>>(Wself1, b1, Wself2, b2,
                                                         W1s, b1s, W2s, b2s);

    const int egrid = (NE + 255) / 256;
    // ---- CSR build (once; rel1/rel2 reused by both layers) ----
    hist_kernel<<<egrid, 256, 0, stream>>>(dst0, cur0, NE);
    hist_kernel<<<egrid, 256, 0, stream>>>(dst1, cur1, NE);
    hist_kernel<<<egrid, 256, 0, stream>>>(dst2, cur2, NE);
    scan_partial_kernel<<<SNB, 256, 0, stream>>>(cur, bsum);
    scan_offsets_kernel<<<1, 256, 0, stream>>>(bsum, boff, rp0, rp1, rp2);
    scan_final_kernel<<<SNB, 256, 0, stream>>>(cur, boff, rp0, rp1, rp2);
    scatter_kernel<<<egrid, 256, 0, stream>>>(src0, dst0, ew0, cur0, col0, wv0, NE);
    scatter_kernel<<<egrid, 256, 0, stream>>>(src1, dst1, ew1, cur1, col1, wv1, NE);
    scatter_kernel<<<egrid, 256, 0, stream>>>(src2, dst2, ew2, cur2, col2, wv2, NE);

    // ---- layer 1 aggregations (gather, normalized) ----
    gather_kernel<<<((size_t)NATTR * 64 + 255) / 256, 256, 0, stream>>>(x_app,  rp0, col0, wv0, agg0, NATTR);
    gather_kernel<<<((size_t)NAPP * 64 + 255) / 256, 256, 0, stream>>>(x_attr, rp1, col1, wv1, agg1, NAPP);
    gather_kernel<<<((size_t)NAPP * 64 + 255) / 256, 256, 0, stream>>>(x_app,  rp2, col2, wv2, agg2, NAPP);

    // ---- layer 1 node updates ----
    node_gemm_kernel<2><<<(NATTR + 63) / 64, 256, 0, stream>>>(
        x_attr, Wself1, agg0, Wneigh1, nullptr, nullptr, b1, h_attr, NATTR, 1);
    node_gemm_kernel<3><<<(NAPP + 63) / 64, 256, 0, stream>>>(
        x_app, W1s, agg1, Wneigh1 + D * D, agg2, Wneigh1 + 2 * D * D,
        b1s, h_app, NAPP, 1);

    // ---- layer 2 (attr output unused by classify -> skip rel0) ----
    gather_kernel<<<((size_t)NAPP * 64 + 255) / 256, 256, 0, stream>>>(h_attr, rp1, col1, wv1, agg1, NAPP);
    gather_kernel<<<((size_t)NAPP * 64 + 255) / 256, 256, 0, stream>>>(h_app,  rp2, col2, wv2, agg2, NAPP);

    node_gemm_kernel<3><<<(NAPP + 63) / 64, 256, 0, stream>>>(
        h_app, W2s, agg1, Wneigh2 + D * D, agg2, Wneigh2 + 2 * D * D,
        b2s, h_app2, NAPP, 0);

    classify_kernel<<<((size_t)NAPP * 64 + 255) / 256, 256, 0, stream>>>(h_app2, Wc, bc, out, NAPP);
}

// Round 4
// 844.213 us; speedup vs baseline: 5.8724x; 1.2498x over previous
//
#include <hip/hip_runtime.h>

#define NAPP  100000
#define NATTR 50000
#define NE    500000
#define D     128
#define NTOT  (NATTR + 2 * NAPP)          // 250000 concatenated histogram
#define SCHUNK 1024
#define SNB   ((NTOT + SCHUNK - 1) / SCHUNK)  // 245 scan blocks

typedef __attribute__((ext_vector_type(8))) short bfrag;   // 8 bf16 (4 VGPRs)
typedef __attribute__((ext_vector_type(4))) float f32x4;   // MFMA accumulator

__device__ __forceinline__ short bf16_rn(float x) {
    union { float f; unsigned u; } a; a.f = x;
    unsigned r = (a.u + 0x7fffu + ((a.u >> 16) & 1u)) >> 16;
    return (short)r;
}
__device__ __forceinline__ float bf16_to_f(short s) {
    union { float f; unsigned u; } a;
    a.u = ((unsigned)(unsigned short)s) << 16;
    return a.f;
}

// ---------------- histogram: hist[dst[e]] += 1 (int atomics) ----------------
__global__ __launch_bounds__(256) void hist_kernel(const int* __restrict__ dst,
                                                   int* __restrict__ hist, int ne) {
    int i = blockIdx.x * 256 + threadIdx.x;
    if (i < ne) atomicAdd(&hist[dst[i]], 1);
}

// ---------------- scan phase A: per-block partial sums ----------------
__global__ __launch_bounds__(256) void scan_partial_kernel(const int* __restrict__ cur,
                                                           int* __restrict__ bsum) {
    int b = blockIdx.x, t = threadIdx.x;
    int4 v = *((const int4*)(cur + b * SCHUNK) + t);
    int s = v.x + v.y + v.z + v.w;
    __shared__ int sd[256];
    sd[t] = s;
    __syncthreads();
    for (int off = 128; off > 0; off >>= 1) {
        if (t < off) sd[t] += sd[t + off];
        __syncthreads();
    }
    if (t == 0) bsum[b] = sd[0];
}

// ---------------- scan phase B: scan of block sums (1 block) ----------------
__global__ __launch_bounds__(256) void scan_offsets_kernel(const int* __restrict__ bsum,
        int* __restrict__ boff, int* __restrict__ rp0, int* __restrict__ rp1,
        int* __restrict__ rp2) {
    int t = threadIdx.x;
    int v = (t < SNB) ? bsum[t] : 0;
    __shared__ int sd[256];
    sd[t] = v;
    __syncthreads();
    for (int off = 1; off < 256; off <<= 1) {
        int u = (t >= off) ? sd[t - off] : 0;
        __syncthreads();
        sd[t] += u;
        __syncthreads();
    }
    boff[t] = sd[t] - v;
    if (t == 0) { rp0[NATTR] = NE; rp1[NAPP] = NE; rp2[NAPP] = NE; }
}

// ---------------- scan phase C: block-local scan + offset ----------------
__global__ __launch_bounds__(256) void scan_final_kernel(int* __restrict__ cur,
        const int* __restrict__ boff, int* __restrict__ rp0, int* __restrict__ rp1,
        int* __restrict__ rp2) {
    int b = blockIdx.x, t = threadIdx.x;
    int base = b * SCHUNK + t * 4;
    int4 v = *(const int4*)(cur + base);
    int s = v.x + v.y + v.z + v.w;
    __shared__ int sd[256];
    sd[t] = s;
    __syncthreads();
    for (int off = 1; off < 256; off <<= 1) {
        int u = (t >= off) ? sd[t - off] : 0;
        __syncthreads();
        sd[t] += u;
        __syncthreads();
    }
    int pre = boff[b] + sd[t] - s;
    int ex[4];
    ex[0] = pre;
    ex[1] = ex[0] + v.x;
    ex[2] = ex[1] + v.y;
    ex[3] = ex[2] + v.z;
    #pragma unroll
    for (int i = 0; i < 4; i++) {
        int idx = base + i;
        if (idx < NTOT) {
            int* rp; int loc; int rbase;
            if (idx < NATTR)             { rp = rp0; loc = idx;                 rbase = 0; }
            else if (idx < NATTR + NAPP) { rp = rp1; loc = idx - NATTR;        rbase = NE; }
            else                         { rp = rp2; loc = idx - NATTR - NAPP; rbase = 2 * NE; }
            int val = ex[i] - rbase;
            rp[loc] = val;
            cur[idx] = val;
        }
    }
}

// ---------------- scatter edges into CSR ----------------
__global__ __launch_bounds__(256) void scatter_kernel(
        const int* __restrict__ src, const int* __restrict__ dst,
        const float* __restrict__ ew, int* __restrict__ cursor,
        int* __restrict__ col, float* __restrict__ wv, int ne) {
    int e = blockIdx.x * 256 + threadIdx.x;
    if (e >= ne) return;
    int p = atomicAdd(&cursor[dst[e]], 1);
    col[p] = src[e];
    wv[p] = ew[e];
}

// ---------------- gather aggregation ----------------
__global__ __launch_bounds__(256) void gather_kernel(const float* __restrict__ x,
        const int* __restrict__ rowptr, const int* __restrict__ col,
        const float* __restrict__ wv, float* __restrict__ agg, int n) {
    int d = (blockIdx.x * 256 + threadIdx.x) >> 6;
    int lane = threadIdx.x & 63;
    if (d >= n) return;
    int s0 = rowptr[d];
    int s1 = rowptr[d + 1];
    float ax = 0.f, ay = 0.f;
    if (s1 > s0) {
        int s = col[s0];
        float w = wv[s0];
        for (int j = s0 + 1; j < s1; j++) {
            int sn = col[j];
            float wn = wv[j];
            float2 v = *(const float2*)(x + (size_t)s * D + lane * 2);
            ax += w * v.x;
            ay += w * v.y;
            s = sn; w = wn;
        }
        float2 v = *(const float2*)(x + (size_t)s * D + lane * 2);
        ax += w * v.x;
        ay += w * v.y;
    }
    float inv = 1.0f / (float)max(s1 - s0, 1);
    *(float2*)(agg + (size_t)d * D + lane * 2) = make_float2(ax * inv, ay * inv);
}

// ---------------- pack weights: fp32 -> hi/lo bf16 in B-fragment order ----------
// 8 matrices: 0:Wself1[0] 1:Wneigh1[0] 2:W1s 3:Wneigh1[1] 4:Wneigh1[2]
//             5:W2s 6:Wneigh2[1] 7:Wneigh2[2]
// frag order: element W[k][n] -> flat ((kc*8+nt)*64 + q*16+c)*8 + j
//             kc=k>>5 q=(k>>3)&3 j=k&7 nt=n>>4 c=n&15
__global__ __launch_bounds__(256) void pack_kernel(
        const float* __restrict__ Wself1, const float* __restrict__ Wneigh1,
        const float* __restrict__ Wself2, const float* __restrict__ Wneigh2,
        const float* __restrict__ b1, const float* __restrict__ b2,
        short* __restrict__ PBh, short* __restrict__ PBl,
        float* __restrict__ b1s, float* __restrict__ b2s) {
    int m = blockIdx.x;
    const float* srcA; const float* srcB = nullptr;
    switch (m) {
        case 0: srcA = Wself1; break;
        case 1: srcA = Wneigh1; break;
        case 2: srcA = Wself1 + D * D; srcB = Wself1 + 2 * D * D; break;
        case 3: srcA = Wneigh1 + D * D; break;
        case 4: srcA = Wneigh1 + 2 * D * D; break;
        case 5: srcA = Wself2 + D * D; srcB = Wself2 + 2 * D * D; break;
        case 6: srcA = Wneigh2 + D * D; break;
        default: srcA = Wneigh2 + 2 * D * D; break;
    }
    short* oh = PBh + (size_t)m * D * D;
    short* ol = PBl + (size_t)m * D * D;
    for (int i = threadIdx.x; i < D * D; i += 256) {
        int k = i >> 7, n = i & 127;
        float v = srcA[i];
        if (srcB) v += srcB[i];
        short hi = bf16_rn(v);
        short lo = bf16_rn(v - bf16_to_f(hi));
        int kc = k >> 5, q = (k >> 3) & 3, j = k & 7, nt = n >> 4, c = n & 15;
        int pos = (((kc * 8 + nt) * 64) + q * 16 + c) * 8 + j;
        oh[pos] = hi;
        ol[pos] = lo;
    }
    if (m == 0 && threadIdx.x < D) {
        int t = threadIdx.x;
        b1s[t] = b1[D + t] + b1[2 * D + t];
        b2s[t] = b2[D + t] + b2[2 * D + t];
    }
}

// ---------------- MFMA node update (split-bf16, 3 products) ----------------
// out = act( sum_s in_s @ W_s + bias ); W pre-packed hi/lo fragments.
// Block: 256 thr (4 waves), tile 64 rows x 128 cols; wave = 16 rows x 128 cols.
#define ASTR 136   // LDS row stride in bf16 (272 B, 16B-aligned, conflict-min)
template<int NS>
__global__ __launch_bounds__(256) void mfma_gemm_kernel(
        const float* __restrict__ in0, const short* __restrict__ B0h, const short* __restrict__ B0l,
        const float* __restrict__ in1, const short* __restrict__ B1h, const short* __restrict__ B1l,
        const float* __restrict__ in2, const short* __restrict__ B2h, const short* __restrict__ B2l,
        const float* __restrict__ bias, float* __restrict__ out,
        int nrows, int dorelu) {
    __shared__ short Ah[64 * ASTR];
    __shared__ short Al[64 * ASTR];
    const int t = threadIdx.x;
    const int w = t >> 6, lane = t & 63;
    const int q = lane >> 4, c = lane & 15;
    const int row0 = blockIdx.x * 64;

    f32x4 acc[8];
    #pragma unroll
    for (int nt = 0; nt < 8; nt++) acc[nt] = (f32x4){0.f, 0.f, 0.f, 0.f};

    const float* ins[3] = { in0, in1, in2 };
    const short* Bhs[3] = { B0h, B1h, B2h };
    const short* Bls[3] = { B0l, B1l, B2l };

    #pragma unroll
    for (int s = 0; s < NS; s++) {
        const float* __restrict__ in = ins[s];
        __syncthreads();
        // stage 64x128 fp32 -> hi/lo bf16 LDS (8 float4 per thread)
        #pragma unroll
        for (int p = 0; p < 8; p++) {
            int id = p * 256 + t;
            int k4 = id & 31, r = id >> 5;
            int row = row0 + r;
            float4 v = make_float4(0.f, 0.f, 0.f, 0.f);
            if (row < nrows) v = *(const float4*)(in + (size_t)row * D + k4 * 4);
            short h0 = bf16_rn(v.x), h1 = bf16_rn(v.y), h2 = bf16_rn(v.z), h3 = bf16_rn(v.w);
            short l0 = bf16_rn(v.x - bf16_to_f(h0));
            short l1 = bf16_rn(v.y - bf16_to_f(h1));
            short l2 = bf16_rn(v.z - bf16_to_f(h2));
            short l3 = bf16_rn(v.w - bf16_to_f(h3));
            *(short4*)&Ah[r * ASTR + k4 * 4] = make_short4(h0, h1, h2, h3);
            *(short4*)&Al[r * ASTR + k4 * 4] = make_short4(l0, l1, l2, l3);
        }
        __syncthreads();
        const bfrag* __restrict__ Bh = (const bfrag*)Bhs[s];
        const bfrag* __restrict__ Bl = (const bfrag*)Bls[s];
        #pragma unroll
        for (int kc = 0; kc < 4; kc++) {
            // A frags: A[m=c][k=kc*32+q*8+j]
            const int aoff = (w * 16 + c) * ASTR + kc * 32 + q * 8;
            bfrag ah = *(const bfrag*)&Ah[aoff];
            bfrag al = *(const bfrag*)&Al[aoff];
            const bfrag* bh = Bh + kc * 8 * 64 + lane;
            const bfrag* bl = Bl + kc * 8 * 64 + lane;
            #pragma unroll
            for (int nt = 0; nt < 8; nt++) {
                bfrag vh = bh[nt * 64];
                bfrag vl = bl[nt * 64];
                acc[nt] = __builtin_amdgcn_mfma_f32_16x16x32_bf16(ah, vh, acc[nt], 0, 0, 0);
                acc[nt] = __builtin_amdgcn_mfma_f32_16x16x32_bf16(ah, vl, acc[nt], 0, 0, 0);
                acc[nt] = __builtin_amdgcn_mfma_f32_16x16x32_bf16(al, vh, acc[nt], 0, 0, 0);
            }
        }
    }

    // epilogue: D row = q*4+r, col = nt*16+c
    #pragma unroll
    for (int nt = 0; nt < 8; nt++) {
        float bv = bias[nt * 16 + c];
        #pragma unroll
        for (int r = 0; r < 4; r++) {
            int row = row0 + w * 16 + q * 4 + r;
            if (row < nrows) {
                float o = acc[nt][r] + bv;
                if (dorelu) o = fmaxf(o, 0.f);
                out[(size_t)row * D + nt * 16 + c] = o;
            }
        }
    }
}

// ---------------- classifier: out[r] = h[r] @ Wc + bc ----------------
__global__ __launch_bounds__(256) void classify_kernel(
        const float* __restrict__ h, const float* __restrict__ Wc,
        const float* __restrict__ bc, float* __restrict__ out, int nrows) {
    int w = (blockIdx.x * 256 + threadIdx.x) >> 6;
    int lane = threadIdx.x & 63;
    if (w >= nrows) return;
    float2 v = *(const float2*)(h + (size_t)w * D + lane * 2);
    float4 wc = *(const float4*)(Wc + lane * 4);
    float p0 = v.x * wc.x + v.y * wc.z;
    float p1 = v.x * wc.y + v.y * wc.w;
    #pragma unroll
    for (int off = 32; off > 0; off >>= 1) {
        p0 += __shfl_down(p0, off);
        p1 += __shfl_down(p1, off);
    }
    if (lane == 0) {
        out[(size_t)w * 2 + 0] = p0 + bc[0];
        out[(size_t)w * 2 + 1] = p1 + bc[1];
    }
}

extern "C" void kernel_launch(void* const* d_in, const int* in_sizes, int n_in,
                              void* d_out, int out_size, void* d_ws, size_t ws_size,
                              hipStream_t stream) {
    const float* x_app   = (const float*)d_in[0];
    const float* x_attr  = (const float*)d_in[1];
    const float* ew0     = (const float*)d_in[2];
    const float* ew1     = (const float*)d_in[3];
    const float* ew2     = (const float*)d_in[4];
    const float* Wself1  = (const float*)d_in[5];
    const float* Wneigh1 = (const float*)d_in[6];
    const float* b1      = (const float*)d_in[7];
    const float* Wself2  = (const float*)d_in[8];
    const float* Wneigh2 = (const float*)d_in[9];
    const float* b2      = (const float*)d_in[10];
    const float* Wc      = (const float*)d_in[11];
    const float* bc      = (const float*)d_in[12];
    const int* src0 = (const int*)d_in[13];
    const int* dst0 = (const int*)d_in[14];
    const int* src1 = (const int*)d_in[15];
    const int* dst1 = (const int*)d_in[16];
    const int* src2 = (const int*)d_in[17];
    const int* dst2 = (const int*)d_in[18];
    float* out = (float*)d_out;

    // ---- workspace layout (4-byte units) ----
    float* ws = (float*)d_ws;
    float* agg0   = ws;                                  // NATTR*D
    float* h_attr = agg0   + (size_t)NATTR * D;          // NATTR*D
    float* agg1   = h_attr + (size_t)NATTR * D;          // NAPP*D
    float* agg2   = agg1   + (size_t)NAPP * D;           // NAPP*D
    float* h_app  = agg2   + (size_t)NAPP * D;           // NAPP*D
    float* b1s    = h_app  + (size_t)NAPP * D;           // D
    float* b2s    = b1s + D;                             // D
    int* cur  = (int*)(b2s + D);                         // SNB*SCHUNK (padded)
    int* cur0 = cur;
    int* cur1 = cur0 + NATTR;
    int* cur2 = cur1 + NAPP;
    int* rp0  = cur + SNB * SCHUNK;                      // NATTR+1 (pad +4)
    int* rp1  = rp0 + NATTR + 4;                         // NAPP+1
    int* rp2  = rp1 + NAPP + 4;                          // NAPP+1
    int* bsum = rp2 + NAPP + 4;                          // 256
    int* boff = bsum + 256;                              // 256
    int* col0 = boff + 256;                              // E
    float* wv0 = (float*)(col0 + NE);                    // E
    int* col1 = (int*)(wv0 + NE);                        // E
    float* wv1 = (float*)(col1 + NE);                    // E
    int* col2 = (int*)(wv1 + NE);                        // E
    float* wv2 = (float*)(col2 + NE);                    // E
    short* PBh = (short*)(wv2 + NE);                     // 8*D*D shorts (256 KB)
    short* PBl = PBh + (size_t)8 * D * D;                // 8*D*D shorts
    float* h_app2 = agg0;  // reuse (agg0 dead after layer-1 attr GEMM)

    // packed weight matrices (hi/lo)
    const size_t MM = (size_t)D * D;
    short* W1self0_h = PBh + 0 * MM; short* W1self0_l = PBl + 0 * MM;
    short* W1ngh0_h  = PBh + 1 * MM; short* W1ngh0_l  = PBl + 1 * MM;
    short* W1s_h     = PBh + 2 * MM; short* W1s_l     = PBl + 2 * MM;
    short* W1ngh1_h  = PBh + 3 * MM; short* W1ngh1_l  = PBl + 3 * MM;
    short* W1ngh2_h  = PBh + 4 * MM; short* W1ngh2_l  = PBl + 4 * MM;
    short* W2s_h     = PBh + 5 * MM; short* W2s_l     = PBl + 5 * MM;
    short* W2ngh1_h  = PBh + 6 * MM; short* W2ngh1_l  = PBl + 6 * MM;
    short* W2ngh2_h  = PBh + 7 * MM; short* W2ngh2_l  = PBl + 7 * MM;

    // zero histogram region incl. scan padding
    hipMemsetAsync(cur, 0, (size_t)SNB * SCHUNK * sizeof(int), stream);

    pack_kernel<<<8, 256, 0, stream>>>(Wself1, Wneigh1, Wself2, Wneigh2,
                                       b1, b2, PBh, PBl, b1s, b2s);

    const int egrid = (NE + 255) / 256;
    // ---- CSR build ----
    hist_kernel<<<egrid, 256, 0, stream>>>(dst0, cur0, NE);
    hist_kernel<<<egrid, 256, 0, stream>>>(dst1, cur1, NE);
    hist_kernel<<<egrid, 256, 0, stream>>>(dst2, cur2, NE);
    scan_partial_kernel<<<SNB, 256, 0, stream>>>(cur, bsum);
    scan_offsets_kernel<<<1, 256, 0, stream>>>(bsum, boff, rp0, rp1, rp2);
    scan_final_kernel<<<SNB, 256, 0, stream>>>(cur, boff, rp0, rp1, rp2);
    scatter_kernel<<<egrid, 256, 0, stream>>>(src0, dst0, ew0, cur0, col0, wv0, NE);
    scatter_kernel<<<egrid, 256, 0, stream>>>(src1, dst1, ew1, cur1, col1, wv1, NE);
    scatter_kernel<<<egrid, 256, 0, stream>>>(src2, dst2, ew2, cur2, col2, wv2, NE);

    // ---- layer 1 aggregations ----
    gather_kernel<<<((size_t)NATTR * 64 + 255) / 256, 256, 0, stream>>>(x_app,  rp0, col0, wv0, agg0, NATTR);
    gather_kernel<<<((size_t)NAPP * 64 + 255) / 256, 256, 0, stream>>>(x_attr, rp1, col1, wv1, agg1, NAPP);
    gather_kernel<<<((size_t)NAPP * 64 + 255) / 256, 256, 0, stream>>>(x_app,  rp2, col2, wv2, agg2, NAPP);

    // ---- layer 1 node updates (MFMA split-bf16) ----
    mfma_gemm_kernel<2><<<(NATTR + 63) / 64, 256, 0, stream>>>(
        x_attr, W1self0_h, W1self0_l, agg0, W1ngh0_h, W1ngh0_l,
        nullptr, nullptr, nullptr, b1, h_attr, NATTR, 1);
    mfma_gemm_kernel<3><<<(NAPP + 63) / 64, 256, 0, stream>>>(
        x_app, W1s_h, W1s_l, agg1, W1ngh1_h, W1ngh1_l, agg2, W1ngh2_h, W1ngh2_l,
        b1s, h_app, NAPP, 1);

    // ---- layer 2 (attr output unused -> skip rel0) ----
    gather_kernel<<<((size_t)NAPP * 64 + 255) / 256, 256, 0, stream>>>(h_attr, rp1, col1, wv1, agg1, NAPP);
    gather_kernel<<<((size_t)NAPP * 64 + 255) / 256, 256, 0, stream>>>(h_app,  rp2, col2, wv2, agg2, NAPP);

    mfma_gemm_kernel<3><<<(NAPP + 63) / 64, 256, 0, stream>>>(
        h_app, W2s_h, W2s_l, agg1, W2ngh1_h, W2ngh1_l, agg2, W2ngh2_h, W2ngh2_l,
        b2s, h_app2, NAPP, 0);

    classify_kernel<<<((size_t)NAPP * 64 + 255) / 256, 256, 0, stream>>>(h_app2, Wc, bc, out, NAPP);
}

// Round 5
// 793.826 us; speedup vs baseline: 6.2451x; 1.0635x over previous
//
#include <hip/hip_runtime.h>

#define NAPP  100000
#define NATTR 50000
#define NE    500000
#define D     128
#define NTOT  (NATTR + 2 * NAPP)
#define SCHUNK 1024
#define SNB   ((NTOT + SCHUNK - 1) / SCHUNK)
#define EGRID ((NE + 255) / 256)

typedef __attribute__((ext_vector_type(8))) short bfrag;
typedef __attribute__((ext_vector_type(4))) float f32x4;

__device__ __forceinline__ short bf16_rn(float x) {
    union { float f; unsigned u; } a; a.f = x;
    unsigned r = (a.u + 0x7fffu + ((a.u >> 16) & 1u)) >> 16;
    return (short)r;
}
__device__ __forceinline__ float bf16_to_f(short s) {
    union { float f; unsigned u; } a;
    a.u = ((unsigned)(unsigned short)s) << 16;
    return a.f;
}

// ---------------- merged histogram over 3 relations ----------------
__global__ __launch_bounds__(256) void hist3_kernel(
        const int* __restrict__ d0, const int* __restrict__ d1, const int* __restrict__ d2,
        int* __restrict__ h0, int* __restrict__ h1, int* __restrict__ h2) {
    int b = blockIdx.x;
    int rel = b / EGRID;
    int i = (b - rel * EGRID) * 256 + threadIdx.x;
    if (i >= NE) return;
    const int* dst = (rel == 0) ? d0 : (rel == 1) ? d1 : d2;
    int* h = (rel == 0) ? h0 : (rel == 1) ? h1 : h2;
    atomicAdd(&h[dst[i]], 1);
}

// ---------------- scan phase A ----------------
__global__ __launch_bounds__(256) void scan_partial_kernel(const int* __restrict__ cur,
                                                           int* __restrict__ bsum) {
    int b = blockIdx.x, t = threadIdx.x;
    int4 v = *((const int4*)(cur + b * SCHUNK) + t);
    int s = v.x + v.y + v.z + v.w;
    __shared__ int sd[256];
    sd[t] = s;
    __syncthreads();
    for (int off = 128; off > 0; off >>= 1) {
        if (t < off) sd[t] += sd[t + off];
        __syncthreads();
    }
    if (t == 0) bsum[b] = sd[0];
}

// ---------------- scan phase B ----------------
__global__ __launch_bounds__(256) void scan_offsets_kernel(const int* __restrict__ bsum,
        int* __restrict__ boff, int* __restrict__ rp0, int* __restrict__ rp1,
        int* __restrict__ rp2) {
    int t = threadIdx.x;
    int v = (t < SNB) ? bsum[t] : 0;
    __shared__ int sd[256];
    sd[t] = v;
    __syncthreads();
    for (int off = 1; off < 256; off <<= 1) {
        int u = (t >= off) ? sd[t - off] : 0;
        __syncthreads();
        sd[t] += u;
        __syncthreads();
    }
    boff[t] = sd[t] - v;
    if (t == 0) { rp0[NATTR] = NE; rp1[NAPP] = NE; rp2[NAPP] = NE; }
}

// ---------------- scan phase C ----------------
__global__ __launch_bounds__(256) void scan_final_kernel(int* __restrict__ cur,
        const int* __restrict__ boff, int* __restrict__ rp0, int* __restrict__ rp1,
        int* __restrict__ rp2) {
    int b = blockIdx.x, t = threadIdx.x;
    int base = b * SCHUNK + t * 4;
    int4 v = *(const int4*)(cur + base);
    int s = v.x + v.y + v.z + v.w;
    __shared__ int sd[256];
    sd[t] = s;
    __syncthreads();
    for (int off = 1; off < 256; off <<= 1) {
        int u = (t >= off) ? sd[t - off] : 0;
        __syncthreads();
        sd[t] += u;
        __syncthreads();
    }
    int pre = boff[b] + sd[t] - s;
    int ex[4];
    ex[0] = pre;
    ex[1] = ex[0] + v.x;
    ex[2] = ex[1] + v.y;
    ex[3] = ex[2] + v.z;
    #pragma unroll
    for (int i = 0; i < 4; i++) {
        int idx = base + i;
        if (idx < NTOT) {
            int* rp; int loc; int rbase;
            if (idx < NATTR)             { rp = rp0; loc = idx;                 rbase = 0; }
            else if (idx < NATTR + NAPP) { rp = rp1; loc = idx - NATTR;        rbase = NE; }
            else                         { rp = rp2; loc = idx - NATTR - NAPP; rbase = 2 * NE; }
            int val = ex[i] - rbase;
            rp[loc] = val;
            cur[idx] = val;
        }
    }
}

// ---------------- merged scatter over 3 relations ----------------
__global__ __launch_bounds__(256) void scatter3_kernel(
        const int* __restrict__ s0, const int* __restrict__ d0, const float* __restrict__ e0,
        int* __restrict__ c0, int* __restrict__ col0, float* __restrict__ wv0,
        const int* __restrict__ s1, const int* __restrict__ d1, const float* __restrict__ e1,
        int* __restrict__ c1, int* __restrict__ col1, float* __restrict__ wv1,
        const int* __restrict__ s2, const int* __restrict__ d2, const float* __restrict__ e2,
        int* __restrict__ c2, int* __restrict__ col2, float* __restrict__ wv2) {
    int b = blockIdx.x;
    int rel = b / EGRID;
    int i = (b - rel * EGRID) * 256 + threadIdx.x;
    if (i >= NE) return;
    const int* src; const int* dst; const float* ew; int* cur; int* col; float* wv;
    if (rel == 0)      { src = s0; dst = d0; ew = e0; cur = c0; col = col0; wv = wv0; }
    else if (rel == 1) { src = s1; dst = d1; ew = e1; cur = c1; col = col1; wv = wv1; }
    else               { src = s2; dst = d2; ew = e2; cur = c2; col = col2; wv = wv2; }
    int p = atomicAdd(&cur[dst[i]], 1);
    col[p] = src[i];
    wv[p] = ew[i];
}

// ---------------- gather aggregation (pipelined, 32 lanes/row) ----------------
// agg[d] = (1/max(deg,1)) * sum ew*x[src]; 4 row-loads in flight (clamped
// indices + zeroed weights keep the batch full on the tail).
__global__ __launch_bounds__(256) void gather_kernel(const float* __restrict__ x,
        const int* __restrict__ rowptr, const int* __restrict__ col,
        const float* __restrict__ wv, float* __restrict__ agg, int n) {
    int d = (blockIdx.x * 256 + threadIdx.x) >> 5;   // half-wave per dst row
    int lane = threadIdx.x & 31;
    if (d >= n) return;
    int s0 = rowptr[d];
    int s1 = rowptr[d + 1];
    float4 acc = make_float4(0.f, 0.f, 0.f, 0.f);
    int last = s1 - 1;
    for (int j = s0; j < s1; j += 4) {
        int i1 = min(j + 1, last), i2 = min(j + 2, last), i3 = min(j + 3, last);
        int a0 = col[j], a1 = col[i1], a2 = col[i2], a3 = col[i3];
        float w0 = wv[j];
        float w1 = (j + 1 < s1) ? wv[i1] : 0.f;
        float w2 = (j + 2 < s1) ? wv[i2] : 0.f;
        float w3 = (j + 3 < s1) ? wv[i3] : 0.f;
        float4 v0 = *(const float4*)(x + (size_t)a0 * D + lane * 4);
        float4 v1 = *(const float4*)(x + (size_t)a1 * D + lane * 4);
        float4 v2 = *(const float4*)(x + (size_t)a2 * D + lane * 4);
        float4 v3 = *(const float4*)(x + (size_t)a3 * D + lane * 4);
        acc.x += w0 * v0.x + w1 * v1.x + w2 * v2.x + w3 * v3.x;
        acc.y += w0 * v0.y + w1 * v1.y + w2 * v2.y + w3 * v3.y;
        acc.z += w0 * v0.z + w1 * v1.z + w2 * v2.z + w3 * v3.z;
        acc.w += w0 * v0.w + w1 * v1.w + w2 * v2.w + w3 * v3.w;
    }
    float inv = 1.0f / (float)max(s1 - s0, 1);
    acc.x *= inv; acc.y *= inv; acc.z *= inv; acc.w *= inv;
    *(float4*)(agg + (size_t)d * D + lane * 4) = acc;
}

// ---------------- pack weights: fp32 -> hi/lo bf16 in B-fragment order --------
__global__ __launch_bounds__(256) void pack_kernel(
        const float* __restrict__ Wself1, const float* __restrict__ Wneigh1,
        const float* __restrict__ Wself2, const float* __restrict__ Wneigh2,
        const float* __restrict__ b1, const float* __restrict__ b2,
        short* __restrict__ PBh, short* __restrict__ PBl,
        float* __restrict__ b1s, float* __restrict__ b2s) {
    int m = blockIdx.x;
    const float* srcA; const float* srcB = nullptr;
    switch (m) {
        case 0: srcA = Wself1; break;
        case 1: srcA = Wneigh1; break;
        case 2: srcA = Wself1 + D * D; srcB = Wself1 + 2 * D * D; break;
        case 3: srcA = Wneigh1 + D * D; break;
        case 4: srcA = Wneigh1 + 2 * D * D; break;
        case 5: srcA = Wself2 + D * D; srcB = Wself2 + 2 * D * D; break;
        case 6: srcA = Wneigh2 + D * D; break;
        default: srcA = Wneigh2 + 2 * D * D; break;
    }
    short* oh = PBh + (size_t)m * D * D;
    short* ol = PBl + (size_t)m * D * D;
    for (int i = threadIdx.x; i < D * D; i += 256) {
        int k = i >> 7, n = i & 127;
        float v = srcA[i];
        if (srcB) v += srcB[i];
        short hi = bf16_rn(v);
        short lo = bf16_rn(v - bf16_to_f(hi));
        int kc = k >> 5, q = (k >> 3) & 3, j = k & 7, nt = n >> 4, c = n & 15;
        int pos = (((kc * 8 + nt) * 64) + q * 16 + c) * 8 + j;
        oh[pos] = hi;
        ol[pos] = lo;
    }
    if (m == 0 && threadIdx.x < D) {
        int t = threadIdx.x;
        b1s[t] = b1[D + t] + b1[2 * D + t];
        b2s[t] = b2[D + t] + b2[2 * D + t];
    }
}

// ---------------- MFMA node update (split-bf16, register double-buffer) ------
#define ASTR 136
template<int NS>
__global__ __launch_bounds__(256) void mfma_gemm_kernel(
        const float* __restrict__ in0, const short* __restrict__ B0h, const short* __restrict__ B0l,
        const float* __restrict__ in1, const short* __restrict__ B1h, const short* __restrict__ B1l,
        const float* __restrict__ in2, const short* __restrict__ B2h, const short* __restrict__ B2l,
        const float* __restrict__ bias, float* __restrict__ out,
        int nrows, int dorelu) {
    __shared__ short Ah[64 * ASTR];
    __shared__ short Al[64 * ASTR];
    const int t = threadIdx.x;
    const int w = t >> 6, lane = t & 63;
    const int q = lane >> 4, c = lane & 15;
    const int row0 = blockIdx.x * 64;

    f32x4 acc[8];
    #pragma unroll
    for (int nt = 0; nt < 8; nt++) acc[nt] = (f32x4){0.f, 0.f, 0.f, 0.f};

    const float* ins[3] = { in0, in1, in2 };
    const short* Bhs[3] = { B0h, B1h, B2h };
    const short* Bls[3] = { B0l, B1l, B2l };

    // preload source 0 tile into registers
    float4 cur[8];
    {
        const float* __restrict__ in = ins[0];
        #pragma unroll
        for (int p = 0; p < 8; p++) {
            int id = p * 256 + t;
            int k4 = id & 31, r = id >> 5;
            int row = row0 + r;
            cur[p] = (row < nrows) ? *(const float4*)(in + (size_t)row * D + k4 * 4)
                                   : make_float4(0.f, 0.f, 0.f, 0.f);
        }
    }

    #pragma unroll
    for (int s = 0; s < NS; s++) {
        float4 nxt[8];
        if (s + 1 < NS) {   // issue next tile's loads before this source's barrier
            const float* __restrict__ in = ins[s + 1];
            #pragma unroll
            for (int p = 0; p < 8; p++) {
                int id = p * 256 + t;
                int k4 = id & 31, r = id >> 5;
                int row = row0 + r;
                nxt[p] = (row < nrows) ? *(const float4*)(in + (size_t)row * D + k4 * 4)
                                       : make_float4(0.f, 0.f, 0.f, 0.f);
            }
        }
        __syncthreads();   // previous compute done -> safe to overwrite LDS
        #pragma unroll
        for (int p = 0; p < 8; p++) {
            int id = p * 256 + t;
            int k4 = id & 31, r = id >> 5;
            float4 v = cur[p];
            short h0 = bf16_rn(v.x), h1 = bf16_rn(v.y), h2 = bf16_rn(v.z), h3 = bf16_rn(v.w);
            short l0 = bf16_rn(v.x - bf16_to_f(h0));
            short l1 = bf16_rn(v.y - bf16_to_f(h1));
            short l2 = bf16_rn(v.z - bf16_to_f(h2));
            short l3 = bf16_rn(v.w - bf16_to_f(h3));
            *(short4*)&Ah[r * ASTR + k4 * 4] = make_short4(h0, h1, h2, h3);
            *(short4*)&Al[r * ASTR + k4 * 4] = make_short4(l0, l1, l2, l3);
        }
        __syncthreads();
        const bfrag* __restrict__ Bh = (const bfrag*)Bhs[s];
        const bfrag* __restrict__ Bl = (const bfrag*)Bls[s];
        #pragma unroll
        for (int kc = 0; kc < 4; kc++) {
            const int aoff = (w * 16 + c) * ASTR + kc * 32 + q * 8;
            bfrag ah = *(const bfrag*)&Ah[aoff];
            bfrag al = *(const bfrag*)&Al[aoff];
            const bfrag* bh = Bh + kc * 8 * 64 + lane;
            const bfrag* bl = Bl + kc * 8 * 64 + lane;
            #pragma unroll
            for (int nt = 0; nt < 8; nt++) {
                bfrag vh = bh[nt * 64];
                bfrag vl = bl[nt * 64];
                acc[nt] = __builtin_amdgcn_mfma_f32_16x16x32_bf16(ah, vh, acc[nt], 0, 0, 0);
                acc[nt] = __builtin_amdgcn_mfma_f32_16x16x32_bf16(ah, vl, acc[nt], 0, 0, 0);
                acc[nt] = __builtin_amdgcn_mfma_f32_16x16x32_bf16(al, vh, acc[nt], 0, 0, 0);
            }
        }
        if (s + 1 < NS) {
            #pragma unroll
            for (int p = 0; p < 8; p++) cur[p] = nxt[p];
        }
    }

    #pragma unroll
    for (int nt = 0; nt < 8; nt++) {
        float bv = bias[nt * 16 + c];
        #pragma unroll
        for (int r = 0; r < 4; r++) {
            int row = row0 + w * 16 + q * 4 + r;
            if (row < nrows) {
                float o = acc[nt][r] + bv;
                if (dorelu) o = fmaxf(o, 0.f);
                out[(size_t)row * D + nt * 16 + c] = o;
            }
        }
    }
}

// ---------------- classifier ----------------
__global__ __launch_bounds__(256) void classify_kernel(
        const float* __restrict__ h, const float* __restrict__ Wc,
        const float* __restrict__ bc, float* __restrict__ out, int nrows) {
    int w = (blockIdx.x * 256 + threadIdx.x) >> 6;
    int lane = threadIdx.x & 63;
    if (w >= nrows) return;
    float2 v = *(const float2*)(h + (size_t)w * D + lane * 2);
    float4 wc = *(const float4*)(Wc + lane * 4);
    float p0 = v.x * wc.x + v.y * wc.z;
    float p1 = v.x * wc.y + v.y * wc.w;
    #pragma unroll
    for (int off = 32; off > 0; off >>= 1) {
        p0 += __shfl_down(p0, off);
        p1 += __shfl_down(p1, off);
    }
    if (lane == 0) {
        out[(size_t)w * 2 + 0] = p0 + bc[0];
        out[(size_t)w * 2 + 1] = p1 + bc[1];
    }
}

extern "C" void kernel_launch(void* const* d_in, const int* in_sizes, int n_in,
                              void* d_out, int out_size, void* d_ws, size_t ws_size,
                              hipStream_t stream) {
    const float* x_app   = (const float*)d_in[0];
    const float* x_attr  = (const float*)d_in[1];
    const float* ew0     = (const float*)d_in[2];
    const float* ew1     = (const float*)d_in[3];
    const float* ew2     = (const float*)d_in[4];
    const float* Wself1  = (const float*)d_in[5];
    const float* Wneigh1 = (const float*)d_in[6];
    const float* b1      = (const float*)d_in[7];
    const float* Wself2  = (const float*)d_in[8];
    const float* Wneigh2 = (const float*)d_in[9];
    const float* b2      = (const float*)d_in[10];
    const float* Wc      = (const float*)d_in[11];
    const float* bc      = (const float*)d_in[12];
    const int* src0 = (const int*)d_in[13];
    const int* dst0 = (const int*)d_in[14];
    const int* src1 = (const int*)d_in[15];
    const int* dst1 = (const int*)d_in[16];
    const int* src2 = (const int*)d_in[17];
    const int* dst2 = (const int*)d_in[18];
    float* out = (float*)d_out;

    // ---- workspace layout (4-byte units) ----
    float* ws = (float*)d_ws;
    float* agg0   = ws;                                  // NATTR*D
    float* h_attr = agg0   + (size_t)NATTR * D;          // NATTR*D
    float* agg1   = h_attr + (size_t)NATTR * D;          // NAPP*D
    float* agg2   = agg1   + (size_t)NAPP * D;           // NAPP*D
    float* h_app  = agg2   + (size_t)NAPP * D;           // NAPP*D
    float* b1s    = h_app  + (size_t)NAPP * D;           // D
    float* b2s    = b1s + D;                             // D
    int* cur  = (int*)(b2s + D);                         // SNB*SCHUNK
    int* cur0 = cur;
    int* cur1 = cur0 + NATTR;
    int* cur2 = cur1 + NAPP;
    int* rp0  = cur + SNB * SCHUNK;                      // NATTR+1 (pad +4)
    int* rp1  = rp0 + NATTR + 4;
    int* rp2  = rp1 + NAPP + 4;
    int* bsum = rp2 + NAPP + 4;                          // 256
    int* boff = bsum + 256;                              // 256
    int* col0 = boff + 256;                              // E
    float* wv0 = (float*)(col0 + NE);                    // E
    int* col1 = (int*)(wv0 + NE);                        // E
    float* wv1 = (float*)(col1 + NE);                    // E
    int* col2 = (int*)(wv1 + NE);                        // E
    float* wv2 = (float*)(col2 + NE);                    // E
    short* PBh = (short*)(wv2 + NE);                     // 8*D*D shorts
    short* PBl = PBh + (size_t)8 * D * D;                // 8*D*D shorts
    float* h_app2 = agg0;  // reuse (agg0+h_attr dead by layer-2 GEMM)

    const size_t MM = (size_t)D * D;
    short* W1self0_h = PBh + 0 * MM; short* W1self0_l = PBl + 0 * MM;
    short* W1ngh0_h  = PBh + 1 * MM; short* W1ngh0_l  = PBl + 1 * MM;
    short* W1s_h     = PBh + 2 * MM; short* W1s_l     = PBl + 2 * MM;
    short* W1ngh1_h  = PBh + 3 * MM; short* W1ngh1_l  = PBl + 3 * MM;
    short* W1ngh2_h  = PBh + 4 * MM; short* W1ngh2_l  = PBl + 4 * MM;
    short* W2s_h     = PBh + 5 * MM; short* W2s_l     = PBl + 5 * MM;
    short* W2ngh1_h  = PBh + 6 * MM; short* W2ngh1_l  = PBl + 6 * MM;
    short* W2ngh2_h  = PBh + 7 * MM; short* W2ngh2_l  = PBl + 7 * MM;

    hipMemsetAsync(cur, 0, (size_t)SNB * SCHUNK * sizeof(int), stream);

    pack_kernel<<<8, 256, 0, stream>>>(Wself1, Wneigh1, Wself2, Wneigh2,
                                       b1, b2, PBh, PBl, b1s, b2s);

    // ---- CSR build ----
    hist3_kernel<<<3 * EGRID, 256, 0, stream>>>(dst0, dst1, dst2, cur0, cur1, cur2);
    scan_partial_kernel<<<SNB, 256, 0, stream>>>(cur, bsum);
    scan_offsets_kernel<<<1, 256, 0, stream>>>(bsum, boff, rp0, rp1, rp2);
    scan_final_kernel<<<SNB, 256, 0, stream>>>(cur, boff, rp0, rp1, rp2);
    scatter3_kernel<<<3 * EGRID, 256, 0, stream>>>(
        src0, dst0, ew0, cur0, col0, wv0,
        src1, dst1, ew1, cur1, col1, wv1,
        src2, dst2, ew2, cur2, col2, wv2);

    // ---- layer 1 aggregations ----
    gather_kernel<<<((size_t)NATTR * 32 + 255) / 256, 256, 0, stream>>>(x_app,  rp0, col0, wv0, agg0, NATTR);
    gather_kernel<<<((size_t)NAPP * 32 + 255) / 256, 256, 0, stream>>>(x_attr, rp1, col1, wv1, agg1, NAPP);
    gather_kernel<<<((size_t)NAPP * 32 + 255) / 256, 256, 0, stream>>>(x_app,  rp2, col2, wv2, agg2, NAPP);

    // ---- layer 1 node updates (MFMA split-bf16) ----
    mfma_gemm_kernel<2><<<(NATTR + 63) / 64, 256, 0, stream>>>(
        x_attr, W1self0_h, W1self0_l, agg0, W1ngh0_h, W1ngh0_l,
        nullptr, nullptr, nullptr, b1, h_attr, NATTR, 1);
    mfma_gemm_kernel<3><<<(NAPP + 63) / 64, 256, 0, stream>>>(
        x_app, W1s_h, W1s_l, agg1, W1ngh1_h, W1ngh1_l, agg2, W1ngh2_h, W1ngh2_l,
        b1s, h_app, NAPP, 1);

    // ---- layer 2 (attr output unused -> skip rel0) ----
    gather_kernel<<<((size_t)NAPP * 32 + 255) / 256, 256, 0, stream>>>(h_attr, rp1, col1, wv1, agg1, NAPP);
    gather_kernel<<<((size_t)NAPP * 32 + 255) / 256, 256, 0, stream>>>(h_app,  rp2, col2, wv2, agg2, NAPP);

    mfma_gemm_kernel<3><<<(NAPP + 63) / 64, 256, 0, stream>>>(
        h_app, W2s_h, W2s_l, agg1, W2ngh1_h, W2ngh1_l, agg2, W2ngh2_h, W2ngh2_l,
        b2s, h_app2, NAPP, 0);

    classify_kernel<<<((size_t)NAPP * 64 + 255) / 256, 256, 0, stream>>>(h_app2, Wc, bc, out, NAPP);
}

// Round 7
// 725.140 us; speedup vs baseline: 6.8367x; 1.0947x over previous
//
#include <hip/hip_runtime.h>

#define NAPP  100000
#define NATTR 50000
#define NE    500000
#define D     128
#define NTOT  (NATTR + 2 * NAPP)
#define SCHUNK 1024
#define SNB   ((NTOT + SCHUNK - 1) / SCHUNK)
#define EGRID ((NE + 255) / 256)

typedef __attribute__((ext_vector_type(8))) short bfrag;
typedef __attribute__((ext_vector_type(4))) float f32x4;

__device__ __forceinline__ short bf16_rn(float x) {
    union { float f; unsigned u; } a; a.f = x;
    unsigned r = (a.u + 0x7fffu + ((a.u >> 16) & 1u)) >> 16;
    return (short)r;
}
__device__ __forceinline__ float bf16_to_f(short s) {
    union { float f; unsigned u; } a;
    a.u = ((unsigned)(unsigned short)s) << 16;
    return a.f;
}

// split two floats into packed bf16-hi pair and bf16-lo (residual) pair.
// hw = (hi(y)<<16)|hi(x), lw = (lo(y)<<16)|lo(x). Pure integer/float scalar
// ops, no vector-element inserts.
__device__ __forceinline__ void split2(float x, float y, unsigned& hw, unsigned& lw) {
    union { float f; unsigned u; } ax, ay;
    ax.f = x; ay.f = y;
    unsigned hx = (ax.u + 0x7fffu + ((ax.u >> 16) & 1u)) >> 16;
    unsigned hy = (ay.u + 0x7fffu + ((ay.u >> 16) & 1u)) >> 16;
    union { unsigned u; float f; } fx, fy;
    fx.u = hx << 16; fy.u = hy << 16;
    union { float f; unsigned u; } rx, ry;
    rx.f = x - fx.f; ry.f = y - fy.f;
    unsigned lx = (rx.u + 0x7fffu + ((rx.u >> 16) & 1u)) >> 16;
    unsigned ly = (ry.u + 0x7fffu + ((ry.u >> 16) & 1u)) >> 16;
    hw = (hy << 16) | (hx & 0xffffu);
    lw = (ly << 16) | (lx & 0xffffu);
}

// ---------------- merged histogram over 3 relations ----------------
__global__ __launch_bounds__(256) void hist3_kernel(
        const int* __restrict__ d0, const int* __restrict__ d1, const int* __restrict__ d2,
        int* __restrict__ h0, int* __restrict__ h1, int* __restrict__ h2) {
    int b = blockIdx.x;
    int rel = b / EGRID;
    int i = (b - rel * EGRID) * 256 + threadIdx.x;
    if (i >= NE) return;
    const int* dst = (rel == 0) ? d0 : (rel == 1) ? d1 : d2;
    int* h = (rel == 0) ? h0 : (rel == 1) ? h1 : h2;
    atomicAdd(&h[dst[i]], 1);
}

// ---------------- scan phase A ----------------
__global__ __launch_bounds__(256) void scan_partial_kernel(const int* __restrict__ cur,
                                                           int* __restrict__ bsum) {
    int b = blockIdx.x, t = threadIdx.x;
    int4 v = *((const int4*)(cur + b * SCHUNK) + t);
    int s = v.x + v.y + v.z + v.w;
    __shared__ int sd[256];
    sd[t] = s;
    __syncthreads();
    for (int off = 128; off > 0; off >>= 1) {
        if (t < off) sd[t] += sd[t + off];
        __syncthreads();
    }
    if (t == 0) bsum[b] = sd[0];
}

// ---------------- scan phase B ----------------
__global__ __launch_bounds__(256) void scan_offsets_kernel(const int* __restrict__ bsum,
        int* __restrict__ boff, int* __restrict__ rp0, int* __restrict__ rp1,
        int* __restrict__ rp2) {
    int t = threadIdx.x;
    int v = (t < SNB) ? bsum[t] : 0;
    __shared__ int sd[256];
    sd[t] = v;
    __syncthreads();
    for (int off = 1; off < 256; off <<= 1) {
        int u = (t >= off) ? sd[t - off] : 0;
        __syncthreads();
        sd[t] += u;
        __syncthreads();
    }
    boff[t] = sd[t] - v;
    if (t == 0) { rp0[NATTR] = NE; rp1[NAPP] = NE; rp2[NAPP] = NE; }
}

// ---------------- scan phase C ----------------
__global__ __launch_bounds__(256) void scan_final_kernel(int* __restrict__ cur,
        const int* __restrict__ boff, int* __restrict__ rp0, int* __restrict__ rp1,
        int* __restrict__ rp2) {
    int b = blockIdx.x, t = threadIdx.x;
    int base = b * SCHUNK + t * 4;
    int4 v = *(const int4*)(cur + base);
    int s = v.x + v.y + v.z + v.w;
    __shared__ int sd[256];
    sd[t] = s;
    __syncthreads();
    for (int off = 1; off < 256; off <<= 1) {
        int u = (t >= off) ? sd[t - off] : 0;
        __syncthreads();
        sd[t] += u;
        __syncthreads();
    }
    int pre = boff[b] + sd[t] - s;
    int ex[4];
    ex[0] = pre;
    ex[1] = ex[0] + v.x;
    ex[2] = ex[1] + v.y;
    ex[3] = ex[2] + v.z;
    #pragma unroll
    for (int i = 0; i < 4; i++) {
        int idx = base + i;
        if (idx < NTOT) {
            int* rp; int loc; int rbase;
            if (idx < NATTR)             { rp = rp0; loc = idx;                 rbase = 0; }
            else if (idx < NATTR + NAPP) { rp = rp1; loc = idx - NATTR;        rbase = NE; }
            else                         { rp = rp2; loc = idx - NATTR - NAPP; rbase = 2 * NE; }
            int val = ex[i] - rbase;
            rp[loc] = val;
            cur[idx] = val;
        }
    }
}

// ---------------- merged scatter over 3 relations ----------------
__global__ __launch_bounds__(256) void scatter3_kernel(
        const int* __restrict__ s0, const int* __restrict__ d0, const float* __restrict__ e0,
        int* __restrict__ c0, int* __restrict__ col0, float* __restrict__ wv0,
        const int* __restrict__ s1, const int* __restrict__ d1, const float* __restrict__ e1,
        int* __restrict__ c1, int* __restrict__ col1, float* __restrict__ wv1,
        const int* __restrict__ s2, const int* __restrict__ d2, const float* __restrict__ e2,
        int* __restrict__ c2, int* __restrict__ col2, float* __restrict__ wv2) {
    int b = blockIdx.x;
    int rel = b / EGRID;
    int i = (b - rel * EGRID) * 256 + threadIdx.x;
    if (i >= NE) return;
    const int* src; const int* dst; const float* ew; int* cur; int* col; float* wv;
    if (rel == 0)      { src = s0; dst = d0; ew = e0; cur = c0; col = col0; wv = wv0; }
    else if (rel == 1) { src = s1; dst = d1; ew = e1; cur = c1; col = col1; wv = wv1; }
    else               { src = s2; dst = d2; ew = e2; cur = c2; col = col2; wv = wv2; }
    int p = atomicAdd(&cur[dst[i]], 1);
    col[p] = src[i];
    wv[p] = ew[i];
}

// ---------------- gather aggregation (pipelined, 32 lanes/row) ----------------
__global__ __launch_bounds__(256) void gather_kernel(const float* __restrict__ x,
        const int* __restrict__ rowptr, const int* __restrict__ col,
        const float* __restrict__ wv, float* __restrict__ agg, int n) {
    int d = (blockIdx.x * 256 + threadIdx.x) >> 5;
    int lane = threadIdx.x & 31;
    if (d >= n) return;
    int s0 = rowptr[d];
    int s1 = rowptr[d + 1];
    float4 acc = make_float4(0.f, 0.f, 0.f, 0.f);
    int last = s1 - 1;
    for (int j = s0; j < s1; j += 4) {
        int i1 = min(j + 1, last), i2 = min(j + 2, last), i3 = min(j + 3, last);
        int a0 = col[j], a1 = col[i1], a2 = col[i2], a3 = col[i3];
        float w0 = wv[j];
        float w1 = (j + 1 < s1) ? wv[i1] : 0.f;
        float w2 = (j + 2 < s1) ? wv[i2] : 0.f;
        float w3 = (j + 3 < s1) ? wv[i3] : 0.f;
        float4 v0 = *(const float4*)(x + (size_t)a0 * D + lane * 4);
        float4 v1 = *(const float4*)(x + (size_t)a1 * D + lane * 4);
        float4 v2 = *(const float4*)(x + (size_t)a2 * D + lane * 4);
        float4 v3 = *(const float4*)(x + (size_t)a3 * D + lane * 4);
        acc.x += w0 * v0.x + w1 * v1.x + w2 * v2.x + w3 * v3.x;
        acc.y += w0 * v0.y + w1 * v1.y + w2 * v2.y + w3 * v3.y;
        acc.z += w0 * v0.z + w1 * v1.z + w2 * v2.z + w3 * v3.z;
        acc.w += w0 * v0.w + w1 * v1.w + w2 * v2.w + w3 * v3.w;
    }
    float inv = 1.0f / (float)max(s1 - s0, 1);
    acc.x *= inv; acc.y *= inv; acc.z *= inv; acc.w *= inv;
    *(float4*)(agg + (size_t)d * D + lane * 4) = acc;
}

// ---------------- pack weights: fp32 -> hi/lo bf16 in B-fragment order --------
__global__ __launch_bounds__(256) void pack_kernel(
        const float* __restrict__ Wself1, const float* __restrict__ Wneigh1,
        const float* __restrict__ Wself2, const float* __restrict__ Wneigh2,
        const float* __restrict__ b1, const float* __restrict__ b2,
        short* __restrict__ PBh, short* __restrict__ PBl,
        float* __restrict__ b1s, float* __restrict__ b2s) {
    int m = blockIdx.x;
    const float* srcA; const float* srcB = nullptr;
    switch (m) {
        case 0: srcA = Wself1; break;
        case 1: srcA = Wneigh1; break;
        case 2: srcA = Wself1 + D * D; srcB = Wself1 + 2 * D * D; break;
        case 3: srcA = Wneigh1 + D * D; break;
        case 4: srcA = Wneigh1 + 2 * D * D; break;
        case 5: srcA = Wself2 + D * D; srcB = Wself2 + 2 * D * D; break;
        case 6: srcA = Wneigh2 + D * D; break;
        default: srcA = Wneigh2 + 2 * D * D; break;
    }
    short* oh = PBh + (size_t)m * D * D;
    short* ol = PBl + (size_t)m * D * D;
    for (int i = threadIdx.x; i < D * D; i += 256) {
        int k = i >> 7, n = i & 127;
        float v = srcA[i];
        if (srcB) v += srcB[i];
        short hi = bf16_rn(v);
        short lo = bf16_rn(v - bf16_to_f(hi));
        int kc = k >> 5, q = (k >> 3) & 3, j = k & 7, nt = n >> 4, c = n & 15;
        int pos = (((kc * 8 + nt) * 64) + q * 16 + c) * 8 + j;
        oh[pos] = hi;
        ol[pos] = lo;
    }
    if (m == 0 && threadIdx.x < D) {
        int t = threadIdx.x;
        b1s[t] = b1[D + t] + b1[2 * D + t];
        b2s[t] = b2[D + t] + b2[2 * D + t];
    }
}

// ---------------- MFMA node update: direct global->reg fragments, no LDS -----
// out = act( sum_s in_s @ W_s + bias )
template<int NS>
__global__ __launch_bounds__(256) void mfma_gemm_kernel(
        const float* __restrict__ in0, const short* __restrict__ B0h, const short* __restrict__ B0l,
        const float* __restrict__ in1, const short* __restrict__ B1h, const short* __restrict__ B1l,
        const float* __restrict__ in2, const short* __restrict__ B2h, const short* __restrict__ B2l,
        const float* __restrict__ bias, float* __restrict__ out,
        int nrows, int dorelu) {
    const int t = threadIdx.x;
    const int w = t >> 6, lane = t & 63;
    const int q = lane >> 4, c = lane & 15;
    const int row0 = blockIdx.x * 64;
    const int myrow = row0 + w * 16 + c;        // A row this lane supplies
    const int arow = min(myrow, nrows - 1);     // clamp; D-rows >= nrows masked at store

    f32x4 acc[8];
    #pragma unroll
    for (int nt = 0; nt < 8; nt++) acc[nt] = (f32x4){0.f, 0.f, 0.f, 0.f};

    const float* ins[3] = { in0, in1, in2 };
    const short* Bhs[3] = { B0h, B1h, B2h };
    const short* Bls[3] = { B0l, B1l, B2l };

    #pragma unroll
    for (int s = 0; s < NS; s++) {
        const float* __restrict__ arp = ins[s] + (size_t)arow * D;
        const bfrag* __restrict__ Bh = (const bfrag*)Bhs[s];
        const bfrag* __restrict__ Bl = (const bfrag*)Bls[s];
        #pragma unroll
        for (int kc = 0; kc < 4; kc++) {
            float4 a0 = *(const float4*)(arp + kc * 32 + q * 8);
            float4 a1 = *(const float4*)(arp + kc * 32 + q * 8 + 4);
            union { unsigned u[4]; bfrag v; } ahu, alu;
            split2(a0.x, a0.y, ahu.u[0], alu.u[0]);
            split2(a0.z, a0.w, ahu.u[1], alu.u[1]);
            split2(a1.x, a1.y, ahu.u[2], alu.u[2]);
            split2(a1.z, a1.w, ahu.u[3], alu.u[3]);
            bfrag ah = ahu.v;
            bfrag al = alu.v;
            const bfrag* bh = Bh + kc * 8 * 64 + lane;
            const bfrag* bl = Bl + kc * 8 * 64 + lane;
            #pragma unroll
            for (int nt = 0; nt < 8; nt++) {
                bfrag vh = bh[nt * 64];
                bfrag vl = bl[nt * 64];
                acc[nt] = __builtin_amdgcn_mfma_f32_16x16x32_bf16(ah, vh, acc[nt], 0, 0, 0);
                acc[nt] = __builtin_amdgcn_mfma_f32_16x16x32_bf16(ah, vl, acc[nt], 0, 0, 0);
                acc[nt] = __builtin_amdgcn_mfma_f32_16x16x32_bf16(al, vh, acc[nt], 0, 0, 0);
            }
        }
    }

    // epilogue: D row = q*4+r, col = nt*16+c
    #pragma unroll
    for (int nt = 0; nt < 8; nt++) {
        float bv = bias[nt * 16 + c];
        #pragma unroll
        for (int r = 0; r < 4; r++) {
            int row = row0 + w * 16 + q * 4 + r;
            if (row < nrows) {
                float o = acc[nt][r] + bv;
                if (dorelu) o = fmaxf(o, 0.f);
                out[(size_t)row * D + nt * 16 + c] = o;
            }
        }
    }
}

// ---------------- classifier: out[r] = h[r] @ Wc + bc ----------------
__global__ __launch_bounds__(256) void classify_kernel(
        const float* __restrict__ h, const float* __restrict__ Wc,
        const float* __restrict__ bc, float* __restrict__ out, int nrows) {
    int w = (blockIdx.x * 256 + threadIdx.x) >> 6;
    int lane = threadIdx.x & 63;
    if (w >= nrows) return;
    float2 v = *(const float2*)(h + (size_t)w * D + lane * 2);
    float4 wc = *(const float4*)(Wc + lane * 4);
    float p0 = v.x * wc.x + v.y * wc.z;
    float p1 = v.x * wc.y + v.y * wc.w;
    #pragma unroll
    for (int off = 32; off > 0; off >>= 1) {
        p0 += __shfl_down(p0, off);
        p1 += __shfl_down(p1, off);
    }
    if (lane == 0) {
        out[(size_t)w * 2 + 0] = p0 + bc[0];
        out[(size_t)w * 2 + 1] = p1 + bc[1];
    }
}

extern "C" void kernel_launch(void* const* d_in, const int* in_sizes, int n_in,
                              void* d_out, int out_size, void* d_ws, size_t ws_size,
                              hipStream_t stream) {
    const float* x_app   = (const float*)d_in[0];
    const float* x_attr  = (const float*)d_in[1];
    const float* ew0     = (const float*)d_in[2];
    const float* ew1     = (const float*)d_in[3];
    const float* ew2     = (const float*)d_in[4];
    const float* Wself1  = (const float*)d_in[5];
    const float* Wneigh1 = (const float*)d_in[6];
    const float* b1      = (const float*)d_in[7];
    const float* Wself2  = (const float*)d_in[8];
    const float* Wneigh2 = (const float*)d_in[9];
    const float* b2      = (const float*)d_in[10];
    const float* Wc      = (const float*)d_in[11];
    const float* bc      = (const float*)d_in[12];
    const int* src0 = (const int*)d_in[13];
    const int* dst0 = (const int*)d_in[14];
    const int* src1 = (const int*)d_in[15];
    const int* dst1 = (const int*)d_in[16];
    const int* src2 = (const int*)d_in[17];
    const int* dst2 = (const int*)d_in[18];
    float* out = (float*)d_out;

    // ---- workspace layout (4-byte units) ----
    float* ws = (float*)d_ws;
    float* agg0   = ws;                                  // NATTR*D
    float* h_attr = agg0   + (size_t)NATTR * D;          // NATTR*D
    float* agg1   = h_attr + (size_t)NATTR * D;          // NAPP*D
    float* agg2   = agg1   + (size_t)NAPP * D;           // NAPP*D
    float* h_app  = agg2   + (size_t)NAPP * D;           // NAPP*D
    float* b1s    = h_app  + (size_t)NAPP * D;           // D
    float* b2s    = b1s + D;                             // D
    int* cur  = (int*)(b2s + D);                         // SNB*SCHUNK
    int* cur0 = cur;
    int* cur1 = cur0 + NATTR;
    int* cur2 = cur1 + NAPP;
    int* rp0  = cur + SNB * SCHUNK;                      // NATTR+1 (pad +4)
    int* rp1  = rp0 + NATTR + 4;
    int* rp2  = rp1 + NAPP + 4;
    int* bsum = rp2 + NAPP + 4;                          // 256
    int* boff = bsum + 256;                              // 256
    int* col0 = boff + 256;                              // E
    float* wv0 = (float*)(col0 + NE);                    // E
    int* col1 = (int*)(wv0 + NE);                        // E
    float* wv1 = (float*)(col1 + NE);                    // E
    int* col2 = (int*)(wv1 + NE);                        // E
    float* wv2 = (float*)(col2 + NE);                    // E
    short* PBh = (short*)(wv2 + NE);                     // 8*D*D shorts
    short* PBl = PBh + (size_t)8 * D * D;                // 8*D*D shorts
    float* h_app2 = agg0;  // reuse agg0+h_attr (both dead by final GEMM)

    const size_t MM = (size_t)D * D;
    short* W1self0_h = PBh + 0 * MM; short* W1self0_l = PBl + 0 * MM;
    short* W1ngh0_h  = PBh + 1 * MM; short* W1ngh0_l  = PBl + 1 * MM;
    short* W1s_h     = PBh + 2 * MM; short* W1s_l     = PBl + 2 * MM;
    short* W1ngh1_h  = PBh + 3 * MM; short* W1ngh1_l  = PBl + 3 * MM;
    short* W1ngh2_h  = PBh + 4 * MM; short* W1ngh2_l  = PBl + 4 * MM;
    short* W2s_h     = PBh + 5 * MM; short* W2s_l     = PBl + 5 * MM;
    short* W2ngh1_h  = PBh + 6 * MM; short* W2ngh1_l  = PBl + 6 * MM;
    short* W2ngh2_h  = PBh + 7 * MM; short* W2ngh2_l  = PBl + 7 * MM;

    hipMemsetAsync(cur, 0, (size_t)SNB * SCHUNK * sizeof(int), stream);

    pack_kernel<<<8, 256, 0, stream>>>(Wself1, Wneigh1, Wself2, Wneigh2,
                                       b1, b2, PBh, PBl, b1s, b2s);

    // ---- CSR build ----
    hist3_kernel<<<3 * EGRID, 256, 0, stream>>>(dst0, dst1, dst2, cur0, cur1, cur2);
    scan_partial_kernel<<<SNB, 256, 0, stream>>>(cur, bsum);
    scan_offsets_kernel<<<1, 256, 0, stream>>>(bsum, boff, rp0, rp1, rp2);
    scan_final_kernel<<<SNB, 256, 0, stream>>>(cur, boff, rp0, rp1, rp2);
    scatter3_kernel<<<3 * EGRID, 256, 0, stream>>>(
        src0, dst0, ew0, cur0, col0, wv0,
        src1, dst1, ew1, cur1, col1, wv1,
        src2, dst2, ew2, cur2, col2, wv2);

    // ---- layer 1 aggregations ----
    gather_kernel<<<((size_t)NATTR * 32 + 255) / 256, 256, 0, stream>>>(x_app,  rp0, col0, wv0, agg0, NATTR);
    gather_kernel<<<((size_t)NAPP * 32 + 255) / 256, 256, 0, stream>>>(x_attr, rp1, col1, wv1, agg1, NAPP);
    gather_kernel<<<((size_t)NAPP * 32 + 255) / 256, 256, 0, stream>>>(x_app,  rp2, col2, wv2, agg2, NAPP);

    // ---- layer 1 node updates (MFMA split-bf16, LDS-free) ----
    mfma_gemm_kernel<2><<<(NATTR + 63) / 64, 256, 0, stream>>>(
        x_attr, W1self0_h, W1self0_l, agg0, W1ngh0_h, W1ngh0_l,
        nullptr, nullptr, nullptr, b1, h_attr, NATTR, 1);
    mfma_gemm_kernel<3><<<(NAPP + 63) / 64, 256, 0, stream>>>(
        x_app, W1s_h, W1s_l, agg1, W1ngh1_h, W1ngh1_l, agg2, W1ngh2_h, W1ngh2_l,
        b1s, h_app, NAPP, 1);

    // ---- layer 2 (attr output unused -> skip rel0) ----
    gather_kernel<<<((size_t)NAPP * 32 + 255) / 256, 256, 0, stream>>>(h_attr, rp1, col1, wv1, agg1, NAPP);
    gather_kernel<<<((size_t)NAPP * 32 + 255) / 256, 256, 0, stream>>>(h_app,  rp2, col2, wv2, agg2, NAPP);

    mfma_gemm_kernel<3><<<(NAPP + 63) / 64, 256, 0, stream>>>(
        h_app, W2s_h, W2s_l, agg1, W2ngh1_h, W2ngh1_l, agg2, W2ngh2_h, W2ngh2_l,
        b2s, h_app2, NAPP, 0);

    classify_kernel<<<((size_t)NAPP * 64 + 255) / 256, 256, 0, stream>>>(h_app2, Wc, bc, out, NAPP);
}

// Round 8
// 671.810 us; speedup vs baseline: 7.3794x; 1.0794x over previous
//
#include <hip/hip_runtime.h>

#define NAPP  100000
#define NATTR 50000
#define NE    500000
#define D     128
#define NTOT  (NATTR + 2 * NAPP)
#define SCHUNK 1024
#define SNB   ((NTOT + SCHUNK - 1) / SCHUNK)
#define EGRID ((NE + 255) / 256)

typedef __attribute__((ext_vector_type(8))) short bfrag;
typedef __attribute__((ext_vector_type(4))) float f32x4;

__device__ __forceinline__ short bf16_rn(float x) {
    union { float f; unsigned u; } a; a.f = x;
    unsigned r = (a.u + 0x7fffu + ((a.u >> 16) & 1u)) >> 16;
    return (short)r;
}
__device__ __forceinline__ float bf16_to_f(short s) {
    union { float f; unsigned u; } a;
    a.u = ((unsigned)(unsigned short)s) << 16;
    return a.f;
}

// split two floats into packed bf16-hi pair and bf16-lo (residual) pair.
// Pure scalar int/float ops — no vector-element inserts (r6 bug).
__device__ __forceinline__ void split2(float x, float y, unsigned& hw, unsigned& lw) {
    union { float f; unsigned u; } ax, ay;
    ax.f = x; ay.f = y;
    unsigned hx = (ax.u + 0x7fffu + ((ax.u >> 16) & 1u)) >> 16;
    unsigned hy = (ay.u + 0x7fffu + ((ay.u >> 16) & 1u)) >> 16;
    union { unsigned u; float f; } fx, fy;
    fx.u = hx << 16; fy.u = hy << 16;
    union { float f; unsigned u; } rx, ry;
    rx.f = x - fx.f; ry.f = y - fy.f;
    unsigned lx = (rx.u + 0x7fffu + ((rx.u >> 16) & 1u)) >> 16;
    unsigned ly = (ry.u + 0x7fffu + ((ry.u >> 16) & 1u)) >> 16;
    hw = (hy << 16) | (hx & 0xffffu);
    lw = (ly << 16) | (lx & 0xffffu);
}

// ---------------- merged histogram over 3 relations ----------------
__global__ __launch_bounds__(256) void hist3_kernel(
        const int* __restrict__ d0, const int* __restrict__ d1, const int* __restrict__ d2,
        int* __restrict__ h0, int* __restrict__ h1, int* __restrict__ h2) {
    int b = blockIdx.x;
    int rel = b / EGRID;
    int i = (b - rel * EGRID) * 256 + threadIdx.x;
    if (i >= NE) return;
    const int* dst = (rel == 0) ? d0 : (rel == 1) ? d1 : d2;
    int* h = (rel == 0) ? h0 : (rel == 1) ? h1 : h2;
    atomicAdd(&h[dst[i]], 1);
}

// ---------------- scan phase A ----------------
__global__ __launch_bounds__(256) void scan_partial_kernel(const int* __restrict__ cur,
                                                           int* __restrict__ bsum) {
    int b = blockIdx.x, t = threadIdx.x;
    int4 v = *((const int4*)(cur + b * SCHUNK) + t);
    int s = v.x + v.y + v.z + v.w;
    __shared__ int sd[256];
    sd[t] = s;
    __syncthreads();
    for (int off = 128; off > 0; off >>= 1) {
        if (t < off) sd[t] += sd[t + off];
        __syncthreads();
    }
    if (t == 0) bsum[b] = sd[0];
}

// ---------------- scan phase B ----------------
__global__ __launch_bounds__(256) void scan_offsets_kernel(const int* __restrict__ bsum,
        int* __restrict__ boff, int* __restrict__ rp0, int* __restrict__ rp1,
        int* __restrict__ rp2) {
    int t = threadIdx.x;
    int v = (t < SNB) ? bsum[t] : 0;
    __shared__ int sd[256];
    sd[t] = v;
    __syncthreads();
    for (int off = 1; off < 256; off <<= 1) {
        int u = (t >= off) ? sd[t - off] : 0;
        __syncthreads();
        sd[t] += u;
        __syncthreads();
    }
    boff[t] = sd[t] - v;
    if (t == 0) { rp0[NATTR] = NE; rp1[NAPP] = NE; rp2[NAPP] = NE; }
}

// ---------------- scan phase C ----------------
__global__ __launch_bounds__(256) void scan_final_kernel(int* __restrict__ cur,
        const int* __restrict__ boff, int* __restrict__ rp0, int* __restrict__ rp1,
        int* __restrict__ rp2) {
    int b = blockIdx.x, t = threadIdx.x;
    int base = b * SCHUNK + t * 4;
    int4 v = *(const int4*)(cur + base);
    int s = v.x + v.y + v.z + v.w;
    __shared__ int sd[256];
    sd[t] = s;
    __syncthreads();
    for (int off = 1; off < 256; off <<= 1) {
        int u = (t >= off) ? sd[t - off] : 0;
        __syncthreads();
        sd[t] += u;
        __syncthreads();
    }
    int pre = boff[b] + sd[t] - s;
    int ex[4];
    ex[0] = pre;
    ex[1] = ex[0] + v.x;
    ex[2] = ex[1] + v.y;
    ex[3] = ex[2] + v.z;
    #pragma unroll
    for (int i = 0; i < 4; i++) {
        int idx = base + i;
        if (idx < NTOT) {
            int* rp; int loc; int rbase;
            if (idx < NATTR)             { rp = rp0; loc = idx;                 rbase = 0; }
            else if (idx < NATTR + NAPP) { rp = rp1; loc = idx - NATTR;        rbase = NE; }
            else                         { rp = rp2; loc = idx - NATTR - NAPP; rbase = 2 * NE; }
            int val = ex[i] - rbase;
            rp[loc] = val;
            cur[idx] = val;
        }
    }
}

// ---------------- merged scatter, packed (src, ew) int2 ----------------
__global__ __launch_bounds__(256) void scatter3_kernel(
        const int* __restrict__ s0, const int* __restrict__ d0, const float* __restrict__ e0,
        int* __restrict__ c0, int2* __restrict__ cw0,
        const int* __restrict__ s1, const int* __restrict__ d1, const float* __restrict__ e1,
        int* __restrict__ c1, int2* __restrict__ cw1,
        const int* __restrict__ s2, const int* __restrict__ d2, const float* __restrict__ e2,
        int* __restrict__ c2, int2* __restrict__ cw2) {
    int b = blockIdx.x;
    int rel = b / EGRID;
    int i = (b - rel * EGRID) * 256 + threadIdx.x;
    if (i >= NE) return;
    const int* src; const int* dst; const float* ew; int* cur; int2* cw;
    if (rel == 0)      { src = s0; dst = d0; ew = e0; cur = c0; cw = cw0; }
    else if (rel == 1) { src = s1; dst = d1; ew = e1; cur = c1; cw = cw1; }
    else               { src = s2; dst = d2; ew = e2; cur = c2; cw = cw2; }
    int p = atomicAdd(&cur[dst[i]], 1);
    int2 v;
    v.x = src[i];
    v.y = __float_as_int(ew[i]);
    cw[p] = v;
}

// ---------------- pack weights: fp32 -> hi/lo bf16 in B-fragment order --------
__global__ __launch_bounds__(256) void pack_kernel(
        const float* __restrict__ Wself1, const float* __restrict__ Wneigh1,
        const float* __restrict__ Wself2, const float* __restrict__ Wneigh2,
        const float* __restrict__ b1, const float* __restrict__ b2,
        short* __restrict__ PBh, short* __restrict__ PBl,
        float* __restrict__ b1s, float* __restrict__ b2s) {
    int m = blockIdx.x;
    const float* srcA; const float* srcB = nullptr;
    switch (m) {
        case 0: srcA = Wself1; break;
        case 1: srcA = Wneigh1; break;
        case 2: srcA = Wself1 + D * D; srcB = Wself1 + 2 * D * D; break;
        case 3: srcA = Wneigh1 + D * D; break;
        case 4: srcA = Wneigh1 + 2 * D * D; break;
        case 5: srcA = Wself2 + D * D; srcB = Wself2 + 2 * D * D; break;
        case 6: srcA = Wneigh2 + D * D; break;
        default: srcA = Wneigh2 + 2 * D * D; break;
    }
    short* oh = PBh + (size_t)m * D * D;
    short* ol = PBl + (size_t)m * D * D;
    for (int i = threadIdx.x; i < D * D; i += 256) {
        int k = i >> 7, n = i & 127;
        float v = srcA[i];
        if (srcB) v += srcB[i];
        short hi = bf16_rn(v);
        short lo = bf16_rn(v - bf16_to_f(hi));
        int kc = k >> 5, q = (k >> 3) & 3, j = k & 7, nt = n >> 4, c = n & 15;
        int pos = (((kc * 8 + nt) * 64) + q * 16 + c) * 8 + j;
        oh[pos] = hi;
        ol[pos] = lo;
    }
    if (m == 0 && threadIdx.x < D) {
        int t = threadIdx.x;
        b1s[t] = b1[D + t] + b1[2 * D + t];
        b2s[t] = b2[D + t] + b2[2 * D + t];
    }
}

// ---------------- fused gather + MFMA node update ----------------
// out = act( in0 @ B0  +  sum_g gather(xs_g, CSR_g) @ Bg  + bias )
// Direct source: per-lane global A-frag loads (r7 path). Gathered sources:
// cooperative gather of the 64-row tile into LDS, then ds_read A-frags.
#define ASTR 132   // LDS row stride in floats (528 B; 16B-aligned, 2-way banks)
template<int NG>
__global__ __launch_bounds__(256) void fused_gemm_kernel(
        const float* __restrict__ in0, const short* __restrict__ B0h, const short* __restrict__ B0l,
        const float* __restrict__ x1, const int* __restrict__ rp1, const int2* __restrict__ cw1,
        const short* __restrict__ B1h, const short* __restrict__ B1l,
        const float* __restrict__ x2, const int* __restrict__ rp2, const int2* __restrict__ cw2,
        const short* __restrict__ B2h, const short* __restrict__ B2l,
        const float* __restrict__ bias, float* __restrict__ out,
        int nrows, int dorelu) {
    __shared__ __align__(16) float At[64 * ASTR];
    const int t = threadIdx.x;
    const int w = t >> 6, lane = t & 63;
    const int q = lane >> 4, c = lane & 15;
    const int row0 = blockIdx.x * 64;
    const int myrow = row0 + w * 16 + c;
    const int arow = min(myrow, nrows - 1);   // clamp; D rows >= nrows masked at store

    f32x4 acc[8];
    #pragma unroll
    for (int nt = 0; nt < 8; nt++) acc[nt] = (f32x4){0.f, 0.f, 0.f, 0.f};

    // ---- direct (self) source: global -> reg fragments ----
    {
        const float* __restrict__ arp = in0 + (size_t)arow * D;
        const bfrag* __restrict__ Bh = (const bfrag*)B0h;
        const bfrag* __restrict__ Bl = (const bfrag*)B0l;
        #pragma unroll
        for (int kc = 0; kc < 4; kc++) {
            float4 a0 = *(const float4*)(arp + kc * 32 + q * 8);
            float4 a1 = *(const float4*)(arp + kc * 32 + q * 8 + 4);
            union { unsigned u[4]; bfrag v; } ahu, alu;
            split2(a0.x, a0.y, ahu.u[0], alu.u[0]);
            split2(a0.z, a0.w, ahu.u[1], alu.u[1]);
            split2(a1.x, a1.y, ahu.u[2], alu.u[2]);
            split2(a1.z, a1.w, ahu.u[3], alu.u[3]);
            bfrag ah = ahu.v, al = alu.v;
            const bfrag* bh = Bh + kc * 512 + lane;
            const bfrag* bl = Bl + kc * 512 + lane;
            #pragma unroll
            for (int nt = 0; nt < 8; nt++) {
                bfrag vh = bh[nt * 64];
                bfrag vl = bl[nt * 64];
                acc[nt] = __builtin_amdgcn_mfma_f32_16x16x32_bf16(ah, vh, acc[nt], 0, 0, 0);
                acc[nt] = __builtin_amdgcn_mfma_f32_16x16x32_bf16(ah, vl, acc[nt], 0, 0, 0);
                acc[nt] = __builtin_amdgcn_mfma_f32_16x16x32_bf16(al, vh, acc[nt], 0, 0, 0);
            }
        }
    }

    // ---- gathered sources: cooperative gather -> LDS -> MFMA ----
    const int grp = t >> 5, l32 = t & 31;   // 8 gather groups of 32 lanes
    #pragma unroll
    for (int g = 0; g < NG; g++) {
        const float* __restrict__ xs = (g == 0) ? x1 : x2;
        const int* __restrict__ rp   = (g == 0) ? rp1 : rp2;
        const int2* __restrict__ cw  = (g == 0) ? cw1 : cw2;
        const short* __restrict__ Bhp = (g == 0) ? B1h : B2h;
        const short* __restrict__ Blp = (g == 0) ? B1l : B2l;

        __syncthreads();   // previous MFMA phase done reading LDS
        #pragma unroll 2
        for (int rr = 0; rr < 8; rr++) {
            int r = grp * 8 + rr;
            int row = row0 + r;
            float4 a = make_float4(0.f, 0.f, 0.f, 0.f);
            if (row < nrows) {
                int s0e = rp[row];
                int s1e = rp[row + 1];
                int last = s1e - 1;
                for (int j = s0e; j < s1e; j += 4) {
                    int i1 = min(j + 1, last), i2 = min(j + 2, last), i3 = min(j + 3, last);
                    int2 e0 = cw[j], e1 = cw[i1], e2 = cw[i2], e3 = cw[i3];
                    float w0 = __int_as_float(e0.y);
                    float w1 = (j + 1 < s1e) ? __int_as_float(e1.y) : 0.f;
                    float w2 = (j + 2 < s1e) ? __int_as_float(e2.y) : 0.f;
                    float w3 = (j + 3 < s1e) ? __int_as_float(e3.y) : 0.f;
                    float4 v0 = *(const float4*)(xs + (size_t)e0.x * D + l32 * 4);
                    float4 v1 = *(const float4*)(xs + (size_t)e1.x * D + l32 * 4);
                    float4 v2 = *(const float4*)(xs + (size_t)e2.x * D + l32 * 4);
                    float4 v3 = *(const float4*)(xs + (size_t)e3.x * D + l32 * 4);
                    a.x += w0 * v0.x + w1 * v1.x + w2 * v2.x + w3 * v3.x;
                    a.y += w0 * v0.y + w1 * v1.y + w2 * v2.y + w3 * v3.y;
                    a.z += w0 * v0.z + w1 * v1.z + w2 * v2.z + w3 * v3.z;
                    a.w += w0 * v0.w + w1 * v1.w + w2 * v2.w + w3 * v3.w;
                }
                float inv = 1.0f / (float)max(s1e - s0e, 1);
                a.x *= inv; a.y *= inv; a.z *= inv; a.w *= inv;
            }
            *(float4*)&At[r * ASTR + l32 * 4] = a;
        }
        __syncthreads();

        const bfrag* __restrict__ Bh = (const bfrag*)Bhp;
        const bfrag* __restrict__ Bl = (const bfrag*)Blp;
        #pragma unroll
        for (int kc = 0; kc < 4; kc++) {
            const float* ap = &At[(w * 16 + c) * ASTR + kc * 32 + q * 8];
            float4 a0 = *(const float4*)ap;
            float4 a1 = *(const float4*)(ap + 4);
            union { unsigned u[4]; bfrag v; } ahu, alu;
            split2(a0.x, a0.y, ahu.u[0], alu.u[0]);
            split2(a0.z, a0.w, ahu.u[1], alu.u[1]);
            split2(a1.x, a1.y, ahu.u[2], alu.u[2]);
            split2(a1.z, a1.w, ahu.u[3], alu.u[3]);
            bfrag ah = ahu.v, al = alu.v;
            const bfrag* bh = Bh + kc * 512 + lane;
            const bfrag* bl = Bl + kc * 512 + lane;
            #pragma unroll
            for (int nt = 0; nt < 8; nt++) {
                bfrag vh = bh[nt * 64];
                bfrag vl = bl[nt * 64];
                acc[nt] = __builtin_amdgcn_mfma_f32_16x16x32_bf16(ah, vh, acc[nt], 0, 0, 0);
                acc[nt] = __builtin_amdgcn_mfma_f32_16x16x32_bf16(ah, vl, acc[nt], 0, 0, 0);
                acc[nt] = __builtin_amdgcn_mfma_f32_16x16x32_bf16(al, vh, acc[nt], 0, 0, 0);
            }
        }
    }

    // ---- epilogue: D row = q*4+r, col = nt*16+c ----
    #pragma unroll
    for (int nt = 0; nt < 8; nt++) {
        float bv = bias[nt * 16 + c];
        #pragma unroll
        for (int r = 0; r < 4; r++) {
            int row = row0 + w * 16 + q * 4 + r;
            if (row < nrows) {
                float o = acc[nt][r] + bv;
                if (dorelu) o = fmaxf(o, 0.f);
                out[(size_t)row * D + nt * 16 + c] = o;
            }
        }
    }
}

// ---------------- classifier: out[r] = h[r] @ Wc + bc ----------------
__global__ __launch_bounds__(256) void classify_kernel(
        const float* __restrict__ h, const float* __restrict__ Wc,
        const float* __restrict__ bc, float* __restrict__ out, int nrows) {
    int w = (blockIdx.x * 256 + threadIdx.x) >> 6;
    int lane = threadIdx.x & 63;
    if (w >= nrows) return;
    float2 v = *(const float2*)(h + (size_t)w * D + lane * 2);
    float4 wc = *(const float4*)(Wc + lane * 4);
    float p0 = v.x * wc.x + v.y * wc.z;
    float p1 = v.x * wc.y + v.y * wc.w;
    #pragma unroll
    for (int off = 32; off > 0; off >>= 1) {
        p0 += __shfl_down(p0, off);
        p1 += __shfl_down(p1, off);
    }
    if (lane == 0) {
        out[(size_t)w * 2 + 0] = p0 + bc[0];
        out[(size_t)w * 2 + 1] = p1 + bc[1];
    }
}

extern "C" void kernel_launch(void* const* d_in, const int* in_sizes, int n_in,
                              void* d_out, int out_size, void* d_ws, size_t ws_size,
                              hipStream_t stream) {
    const float* x_app   = (const float*)d_in[0];
    const float* x_attr  = (const float*)d_in[1];
    const float* ew0     = (const float*)d_in[2];
    const float* ew1     = (const float*)d_in[3];
    const float* ew2     = (const float*)d_in[4];
    const float* Wself1  = (const float*)d_in[5];
    const float* Wneigh1 = (const float*)d_in[6];
    const float* b1      = (const float*)d_in[7];
    const float* Wself2  = (const float*)d_in[8];
    const float* Wneigh2 = (const float*)d_in[9];
    const float* b2      = (const float*)d_in[10];
    const float* Wc      = (const float*)d_in[11];
    const float* bc      = (const float*)d_in[12];
    const int* src0 = (const int*)d_in[13];
    const int* dst0 = (const int*)d_in[14];
    const int* src1 = (const int*)d_in[15];
    const int* dst1 = (const int*)d_in[16];
    const int* src2 = (const int*)d_in[17];
    const int* dst2 = (const int*)d_in[18];
    float* out = (float*)d_out;

    // ---- workspace layout (4-byte units; all block starts even -> int2 8B ok) --
    float* ws = (float*)d_ws;
    float* h_attr = ws;                                  // NATTR*D
    float* h_app  = h_attr + (size_t)NATTR * D;          // NAPP*D
    float* h_app2 = h_app  + (size_t)NAPP * D;           // NAPP*D
    float* b1s    = h_app2 + (size_t)NAPP * D;           // D
    float* b2s    = b1s + D;                             // D
    int* cur  = (int*)(b2s + D);                         // SNB*SCHUNK
    int* cur0 = cur;
    int* cur1 = cur0 + NATTR;
    int* cur2 = cur1 + NAPP;
    int* rp0  = cur + SNB * SCHUNK;                      // NATTR+4
    int* rp1  = rp0 + NATTR + 4;                         // NAPP+4
    int* rp2  = rp1 + NAPP + 4;                          // NAPP+4
    int* bsum = rp2 + NAPP + 4;                          // 256
    int* boff = bsum + 256;                              // 256
    int2* cw0 = (int2*)(boff + 256);                     // NE int2
    int2* cw1 = cw0 + NE;                                // NE int2
    int2* cw2 = cw1 + NE;                                // NE int2
    short* PBh = (short*)(cw2 + NE);                     // 8*D*D shorts
    short* PBl = PBh + (size_t)8 * D * D;                // 8*D*D shorts

    const size_t MM = (size_t)D * D;
    short* W1self0_h = PBh + 0 * MM; short* W1self0_l = PBl + 0 * MM;
    short* W1ngh0_h  = PBh + 1 * MM; short* W1ngh0_l  = PBl + 1 * MM;
    short* W1s_h     = PBh + 2 * MM; short* W1s_l     = PBl + 2 * MM;
    short* W1ngh1_h  = PBh + 3 * MM; short* W1ngh1_l  = PBl + 3 * MM;
    short* W1ngh2_h  = PBh + 4 * MM; short* W1ngh2_l  = PBl + 4 * MM;
    short* W2s_h     = PBh + 5 * MM; short* W2s_l     = PBl + 5 * MM;
    short* W2ngh1_h  = PBh + 6 * MM; short* W2ngh1_l  = PBl + 6 * MM;
    short* W2ngh2_h  = PBh + 7 * MM; short* W2ngh2_l  = PBl + 7 * MM;

    hipMemsetAsync(cur, 0, (size_t)SNB * SCHUNK * sizeof(int), stream);

    pack_kernel<<<8, 256, 0, stream>>>(Wself1, Wneigh1, Wself2, Wneigh2,
                                       b1, b2, PBh, PBl, b1s, b2s);

    // ---- CSR build ----
    hist3_kernel<<<3 * EGRID, 256, 0, stream>>>(dst0, dst1, dst2, cur0, cur1, cur2);
    scan_partial_kernel<<<SNB, 256, 0, stream>>>(cur, bsum);
    scan_offsets_kernel<<<1, 256, 0, stream>>>(bsum, boff, rp0, rp1, rp2);
    scan_final_kernel<<<SNB, 256, 0, stream>>>(cur, boff, rp0, rp1, rp2);
    scatter3_kernel<<<3 * EGRID, 256, 0, stream>>>(
        src0, dst0, ew0, cur0, cw0,
        src1, dst1, ew1, cur1, cw1,
        src2, dst2, ew2, cur2, cw2);

    // ---- layer 1 (fused gather + GEMM) ----
    fused_gemm_kernel<1><<<(NATTR + 63) / 64, 256, 0, stream>>>(
        x_attr, W1self0_h, W1self0_l,
        x_app, rp0, cw0, W1ngh0_h, W1ngh0_l,
        nullptr, nullptr, nullptr, nullptr, nullptr,
        b1, h_attr, NATTR, 1);
    fused_gemm_kernel<2><<<(NAPP + 63) / 64, 256, 0, stream>>>(
        x_app, W1s_h, W1s_l,
        x_attr, rp1, cw1, W1ngh1_h, W1ngh1_l,
        x_app,  rp2, cw2, W1ngh2_h, W1ngh2_l,
        b1s, h_app, NAPP, 1);

    // ---- layer 2 (attr output unused -> skip rel0) ----
    fused_gemm_kernel<2><<<(NAPP + 63) / 64, 256, 0, stream>>>(
        h_app, W2s_h, W2s_l,
        h_attr, rp1, cw1, W2ngh1_h, W2ngh1_l,
        h_app,  rp2, cw2, W2ngh2_h, W2ngh2_l,
        b2s, h_app2, NAPP, 0);

    classify_kernel<<<((size_t)NAPP * 64 + 255) / 256, 256, 0, stream>>>(h_app2, Wc, bc, out, NAPP);
}

// Round 9
// 565.079 us; speedup vs baseline: 8.7732x; 1.1889x over previous
//
#include <hip/hip_runtime.h>

#define NAPP  100000
#define NATTR 50000
#define NE    500000
#define D     128
#define NTOT  (NATTR + 2 * NAPP)
#define SCHUNK 1024
#define SNB   ((NTOT + SCHUNK - 1) / SCHUNK)
#define EGRID ((NE + 255) / 256)

typedef __attribute__((ext_vector_type(8))) short bfrag;
typedef __attribute__((ext_vector_type(4))) float f32x4;

__device__ __forceinline__ short bf16_rn(float x) {
    union { float f; unsigned u; } a; a.f = x;
    unsigned r = (a.u + 0x7fffu + ((a.u >> 16) & 1u)) >> 16;
    return (short)r;
}
__device__ __forceinline__ float bf16_to_f(short s) {
    union { float f; unsigned u; } a;
    a.u = ((unsigned)(unsigned short)s) << 16;
    return a.f;
}

// split two floats into packed bf16-hi pair and bf16-lo (residual) pair.
// Pure scalar int/float ops — no vector-element inserts (r6 bug).
__device__ __forceinline__ void split2(float x, float y, unsigned& hw, unsigned& lw) {
    union { float f; unsigned u; } ax, ay;
    ax.f = x; ay.f = y;
    unsigned hx = (ax.u + 0x7fffu + ((ax.u >> 16) & 1u)) >> 16;
    unsigned hy = (ay.u + 0x7fffu + ((ay.u >> 16) & 1u)) >> 16;
    union { unsigned u; float f; } fx, fy;
    fx.u = hx << 16; fy.u = hy << 16;
    union { float f; unsigned u; } rx, ry;
    rx.f = x - fx.f; ry.f = y - fy.f;
    unsigned lx = (rx.u + 0x7fffu + ((rx.u >> 16) & 1u)) >> 16;
    unsigned ly = (ry.u + 0x7fffu + ((ry.u >> 16) & 1u)) >> 16;
    hw = (hy << 16) | (hx & 0xffffu);
    lw = (ly << 16) | (lx & 0xffffu);
}

// ---------------- merged histogram over 3 relations ----------------
__global__ __launch_bounds__(256) void hist3_kernel(
        const int* __restrict__ d0, const int* __restrict__ d1, const int* __restrict__ d2,
        int* __restrict__ h0, int* __restrict__ h1, int* __restrict__ h2) {
    int b = blockIdx.x;
    int rel = b / EGRID;
    int i = (b - rel * EGRID) * 256 + threadIdx.x;
    if (i >= NE) return;
    const int* dst = (rel == 0) ? d0 : (rel == 1) ? d1 : d2;
    int* h = (rel == 0) ? h0 : (rel == 1) ? h1 : h2;
    atomicAdd(&h[dst[i]], 1);
}

// ---------------- scan phase A ----------------
__global__ __launch_bounds__(256) void scan_partial_kernel(const int* __restrict__ cur,
                                                           int* __restrict__ bsum) {
    int b = blockIdx.x, t = threadIdx.x;
    int4 v = *((const int4*)(cur + b * SCHUNK) + t);
    int s = v.x + v.y + v.z + v.w;
    __shared__ int sd[256];
    sd[t] = s;
    __syncthreads();
    for (int off = 128; off > 0; off >>= 1) {
        if (t < off) sd[t] += sd[t + off];
        __syncthreads();
    }
    if (t == 0) bsum[b] = sd[0];
}

// ---------------- scan phase B ----------------
__global__ __launch_bounds__(256) void scan_offsets_kernel(const int* __restrict__ bsum,
        int* __restrict__ boff, int* __restrict__ rp0, int* __restrict__ rp1,
        int* __restrict__ rp2) {
    int t = threadIdx.x;
    int v = (t < SNB) ? bsum[t] : 0;
    __shared__ int sd[256];
    sd[t] = v;
    __syncthreads();
    for (int off = 1; off < 256; off <<= 1) {
        int u = (t >= off) ? sd[t - off] : 0;
        __syncthreads();
        sd[t] += u;
        __syncthreads();
    }
    boff[t] = sd[t] - v;
    if (t == 0) { rp0[NATTR] = NE; rp1[NAPP] = NE; rp2[NAPP] = NE; }
}

// ---------------- scan phase C ----------------
__global__ __launch_bounds__(256) void scan_final_kernel(int* __restrict__ cur,
        const int* __restrict__ boff, int* __restrict__ rp0, int* __restrict__ rp1,
        int* __restrict__ rp2) {
    int b = blockIdx.x, t = threadIdx.x;
    int base = b * SCHUNK + t * 4;
    int4 v = *(const int4*)(cur + base);
    int s = v.x + v.y + v.z + v.w;
    __shared__ int sd[256];
    sd[t] = s;
    __syncthreads();
    for (int off = 1; off < 256; off <<= 1) {
        int u = (t >= off) ? sd[t - off] : 0;
        __syncthreads();
        sd[t] += u;
        __syncthreads();
    }
    int pre = boff[b] + sd[t] - s;
    int ex[4];
    ex[0] = pre;
    ex[1] = ex[0] + v.x;
    ex[2] = ex[1] + v.y;
    ex[3] = ex[2] + v.z;
    #pragma unroll
    for (int i = 0; i < 4; i++) {
        int idx = base + i;
        if (idx < NTOT) {
            int* rp; int loc; int rbase;
            if (idx < NATTR)             { rp = rp0; loc = idx;                 rbase = 0; }
            else if (idx < NATTR + NAPP) { rp = rp1; loc = idx - NATTR;        rbase = NE; }
            else                         { rp = rp2; loc = idx - NATTR - NAPP; rbase = 2 * NE; }
            int val = ex[i] - rbase;
            rp[loc] = val;
            cur[idx] = val;
        }
    }
}

// ---------------- merged scatter, packed (src, ew) int2 ----------------
__global__ __launch_bounds__(256) void scatter3_kernel(
        const int* __restrict__ s0, const int* __restrict__ d0, const float* __restrict__ e0,
        int* __restrict__ c0, int2* __restrict__ cw0,
        const int* __restrict__ s1, const int* __restrict__ d1, const float* __restrict__ e1,
        int* __restrict__ c1, int2* __restrict__ cw1,
        const int* __restrict__ s2, const int* __restrict__ d2, const float* __restrict__ e2,
        int* __restrict__ c2, int2* __restrict__ cw2) {
    int b = blockIdx.x;
    int rel = b / EGRID;
    int i = (b - rel * EGRID) * 256 + threadIdx.x;
    if (i >= NE) return;
    const int* src; const int* dst; const float* ew; int* cur; int2* cw;
    if (rel == 0)      { src = s0; dst = d0; ew = e0; cur = c0; cw = cw0; }
    else if (rel == 1) { src = s1; dst = d1; ew = e1; cur = c1; cw = cw1; }
    else               { src = s2; dst = d2; ew = e2; cur = c2; cw = cw2; }
    int p = atomicAdd(&cur[dst[i]], 1);
    int2 v;
    v.x = src[i];
    v.y = __float_as_int(ew[i]);
    cw[p] = v;
}

// ---------------- pack weights + layer-2 collapsed constants ----------------
// blocks 0..7: W fp32 -> hi/lo bf16 in B-fragment order (layer-1 + unused W2)
// block 8: Cs = (W2self1+W2self2)@Wc, C1 = W2neigh1@Wc, C2 = W2neigh2@Wc,
//          bconst = (b2_1+b2_2)@Wc + bc   (all exact fp32)
__global__ __launch_bounds__(256) void pack_kernel(
        const float* __restrict__ Wself1, const float* __restrict__ Wneigh1,
        const float* __restrict__ Wself2, const float* __restrict__ Wneigh2,
        const float* __restrict__ b1, const float* __restrict__ b2,
        const float* __restrict__ Wc, const float* __restrict__ bc,
        short* __restrict__ PBh, short* __restrict__ PBl,
        float* __restrict__ b1s, float* __restrict__ b2s,
        float* __restrict__ Cs, float* __restrict__ C1, float* __restrict__ C2,
        float* __restrict__ bconst) {
    int m = blockIdx.x;
    if (m == 8) {
        int tid = threadIdx.x;
        int k = tid >> 1, j = tid & 1;
        const float* Wn1 = Wneigh2 + D * D;
        const float* Wn2 = Wneigh2 + 2 * D * D;
        const float* Ws1 = Wself2 + D * D;
        const float* Ws2 = Wself2 + 2 * D * D;
        float ss = 0.f, s1 = 0.f, s2 = 0.f;
        for (int tt = 0; tt < D; tt++) {
            float wc = Wc[tt * 2 + j];
            ss += (Ws1[k * D + tt] + Ws2[k * D + tt]) * wc;
            s1 += Wn1[k * D + tt] * wc;
            s2 += Wn2[k * D + tt] * wc;
        }
        Cs[tid] = ss; C1[tid] = s1; C2[tid] = s2;
        if (tid < 2) {
            float s = bc[tid];
            for (int tt = 0; tt < D; tt++)
                s += (b2[D + tt] + b2[2 * D + tt]) * Wc[tt * 2 + tid];
            bconst[tid] = s;
        }
        return;
    }
    const float* srcA; const float* srcB = nullptr;
    switch (m) {
        case 0: srcA = Wself1; break;
        case 1: srcA = Wneigh1; break;
        case 2: srcA = Wself1 + D * D; srcB = Wself1 + 2 * D * D; break;
        case 3: srcA = Wneigh1 + D * D; break;
        case 4: srcA = Wneigh1 + 2 * D * D; break;
        case 5: srcA = Wself2 + D * D; srcB = Wself2 + 2 * D * D; break;
        case 6: srcA = Wneigh2 + D * D; break;
        default: srcA = Wneigh2 + 2 * D * D; break;
    }
    short* oh = PBh + (size_t)m * D * D;
    short* ol = PBl + (size_t)m * D * D;
    for (int i = threadIdx.x; i < D * D; i += 256) {
        int k = i >> 7, n = i & 127;
        float v = srcA[i];
        if (srcB) v += srcB[i];
        short hi = bf16_rn(v);
        short lo = bf16_rn(v - bf16_to_f(hi));
        int kc = k >> 5, q = (k >> 3) & 3, j = k & 7, nt = n >> 4, c = n & 15;
        int pos = (((kc * 8 + nt) * 64) + q * 16 + c) * 8 + j;
        oh[pos] = hi;
        ol[pos] = lo;
    }
    if (m == 0 && threadIdx.x < D) {
        int t = threadIdx.x;
        b1s[t] = b1[D + t] + b1[2 * D + t];
        b2s[t] = b2[D + t] + b2[2 * D + t];
    }
}

// ---------------- fused gather + MFMA node update (layer 1) ----------------
#define ASTR 132
template<int NG>
__global__ __launch_bounds__(256) void fused_gemm_kernel(
        const float* __restrict__ in0, const short* __restrict__ B0h, const short* __restrict__ B0l,
        const float* __restrict__ x1, const int* __restrict__ rp1, const int2* __restrict__ cw1,
        const short* __restrict__ B1h, const short* __restrict__ B1l,
        const float* __restrict__ x2, const int* __restrict__ rp2, const int2* __restrict__ cw2,
        const short* __restrict__ B2h, const short* __restrict__ B2l,
        const float* __restrict__ bias, float* __restrict__ out,
        int nrows, int dorelu) {
    __shared__ __align__(16) float At[64 * ASTR];
    const int t = threadIdx.x;
    const int w = t >> 6, lane = t & 63;
    const int q = lane >> 4, c = lane & 15;
    const int row0 = blockIdx.x * 64;
    const int myrow = row0 + w * 16 + c;
    const int arow = min(myrow, nrows - 1);

    f32x4 acc[8];
    #pragma unroll
    for (int nt = 0; nt < 8; nt++) acc[nt] = (f32x4){0.f, 0.f, 0.f, 0.f};

    // ---- direct (self) source: global -> reg fragments ----
    {
        const float* __restrict__ arp = in0 + (size_t)arow * D;
        const bfrag* __restrict__ Bh = (const bfrag*)B0h;
        const bfrag* __restrict__ Bl = (const bfrag*)B0l;
        #pragma unroll
        for (int kc = 0; kc < 4; kc++) {
            float4 a0 = *(const float4*)(arp + kc * 32 + q * 8);
            float4 a1 = *(const float4*)(arp + kc * 32 + q * 8 + 4);
            union { unsigned u[4]; bfrag v; } ahu, alu;
            split2(a0.x, a0.y, ahu.u[0], alu.u[0]);
            split2(a0.z, a0.w, ahu.u[1], alu.u[1]);
            split2(a1.x, a1.y, ahu.u[2], alu.u[2]);
            split2(a1.z, a1.w, ahu.u[3], alu.u[3]);
            bfrag ah = ahu.v, al = alu.v;
            const bfrag* bh = Bh + kc * 512 + lane;
            const bfrag* bl = Bl + kc * 512 + lane;
            #pragma unroll
            for (int nt = 0; nt < 8; nt++) {
                bfrag vh = bh[nt * 64];
                bfrag vl = bl[nt * 64];
                acc[nt] = __builtin_amdgcn_mfma_f32_16x16x32_bf16(ah, vh, acc[nt], 0, 0, 0);
                acc[nt] = __builtin_amdgcn_mfma_f32_16x16x32_bf16(ah, vl, acc[nt], 0, 0, 0);
                acc[nt] = __builtin_amdgcn_mfma_f32_16x16x32_bf16(al, vh, acc[nt], 0, 0, 0);
            }
        }
    }

    // ---- gathered sources: cooperative gather -> LDS -> MFMA ----
    const int grp = t >> 5, l32 = t & 31;
    #pragma unroll
    for (int g = 0; g < NG; g++) {
        const float* __restrict__ xs = (g == 0) ? x1 : x2;
        const int* __restrict__ rp   = (g == 0) ? rp1 : rp2;
        const int2* __restrict__ cw  = (g == 0) ? cw1 : cw2;
        const short* __restrict__ Bhp = (g == 0) ? B1h : B2h;
        const short* __restrict__ Blp = (g == 0) ? B1l : B2l;

        __syncthreads();
        #pragma unroll 2
        for (int rr = 0; rr < 8; rr++) {
            int r = grp * 8 + rr;
            int row = row0 + r;
            float4 a = make_float4(0.f, 0.f, 0.f, 0.f);
            if (row < nrows) {
                int s0e = rp[row];
                int s1e = rp[row + 1];
                int last = s1e - 1;
                for (int j = s0e; j < s1e; j += 4) {
                    int i1 = min(j + 1, last), i2 = min(j + 2, last), i3 = min(j + 3, last);
                    int2 e0 = cw[j], e1 = cw[i1], e2 = cw[i2], e3 = cw[i3];
                    float w0 = __int_as_float(e0.y);
                    float w1 = (j + 1 < s1e) ? __int_as_float(e1.y) : 0.f;
                    float w2 = (j + 2 < s1e) ? __int_as_float(e2.y) : 0.f;
                    float w3 = (j + 3 < s1e) ? __int_as_float(e3.y) : 0.f;
                    float4 v0 = *(const float4*)(xs + (size_t)e0.x * D + l32 * 4);
                    float4 v1 = *(const float4*)(xs + (size_t)e1.x * D + l32 * 4);
                    float4 v2 = *(const float4*)(xs + (size_t)e2.x * D + l32 * 4);
                    float4 v3 = *(const float4*)(xs + (size_t)e3.x * D + l32 * 4);
                    a.x += w0 * v0.x + w1 * v1.x + w2 * v2.x + w3 * v3.x;
                    a.y += w0 * v0.y + w1 * v1.y + w2 * v2.y + w3 * v3.y;
                    a.z += w0 * v0.z + w1 * v1.z + w2 * v2.z + w3 * v3.z;
                    a.w += w0 * v0.w + w1 * v1.w + w2 * v2.w + w3 * v3.w;
                }
                float inv = 1.0f / (float)max(s1e - s0e, 1);
                a.x *= inv; a.y *= inv; a.z *= inv; a.w *= inv;
            }
            *(float4*)&At[r * ASTR + l32 * 4] = a;
        }
        __syncthreads();

        const bfrag* __restrict__ Bh = (const bfrag*)Bhp;
        const bfrag* __restrict__ Bl = (const bfrag*)Blp;
        #pragma unroll
        for (int kc = 0; kc < 4; kc++) {
            const float* ap = &At[(w * 16 + c) * ASTR + kc * 32 + q * 8];
            float4 a0 = *(const float4*)ap;
            float4 a1 = *(const float4*)(ap + 4);
            union { unsigned u[4]; bfrag v; } ahu, alu;
            split2(a0.x, a0.y, ahu.u[0], alu.u[0]);
            split2(a0.z, a0.w, ahu.u[1], alu.u[1]);
            split2(a1.x, a1.y, ahu.u[2], alu.u[2]);
            split2(a1.z, a1.w, ahu.u[3], alu.u[3]);
            bfrag ah = ahu.v, al = alu.v;
            const bfrag* bh = Bh + kc * 512 + lane;
            const bfrag* bl = Bl + kc * 512 + lane;
            #pragma unroll
            for (int nt = 0; nt < 8; nt++) {
                bfrag vh = bh[nt * 64];
                bfrag vl = bl[nt * 64];
                acc[nt] = __builtin_amdgcn_mfma_f32_16x16x32_bf16(ah, vh, acc[nt], 0, 0, 0);
                acc[nt] = __builtin_amdgcn_mfma_f32_16x16x32_bf16(ah, vl, acc[nt], 0, 0, 0);
                acc[nt] = __builtin_amdgcn_mfma_f32_16x16x32_bf16(al, vh, acc[nt], 0, 0, 0);
            }
        }
    }

    // ---- epilogue: D row = q*4+r, col = nt*16+c ----
    #pragma unroll
    for (int nt = 0; nt < 8; nt++) {
        float bv = bias[nt * 16 + c];
        #pragma unroll
        for (int r = 0; r < 4; r++) {
            int row = row0 + w * 16 + q * 4 + r;
            if (row < nrows) {
                float o = acc[nt][r] + bv;
                if (dorelu) o = fmaxf(o, 0.f);
                out[(size_t)row * D + nt * 16 + c] = o;
            }
        }
    }
}

// ---------------- skinny: z[r][0..1] = h[r] @ C (128x2), wave per row --------
__global__ __launch_bounds__(256) void skinny1_kernel(const float* __restrict__ h,
        const float* __restrict__ C, float* __restrict__ z, int n) {
    int r = (blockIdx.x * 256 + threadIdx.x) >> 6;
    int l = threadIdx.x & 63;
    if (r >= n) return;
    float2 v = *(const float2*)(h + (size_t)r * D + l * 2);
    float4 c = *(const float4*)(C + l * 4);
    float p0 = v.x * c.x + v.y * c.z;
    float p1 = v.x * c.y + v.y * c.w;
    #pragma unroll
    for (int off = 32; off > 0; off >>= 1) {
        p0 += __shfl_down(p0, off);
        p1 += __shfl_down(p1, off);
    }
    if (l == 0) { z[(size_t)r * 2] = p0; z[(size_t)r * 2 + 1] = p1; }
}

// ---------------- skinny x2: zs = h@Cs, z2 = h@C2 in one pass ----------------
__global__ __launch_bounds__(256) void skinny2_kernel(const float* __restrict__ h,
        const float* __restrict__ Cs, const float* __restrict__ C2,
        float* __restrict__ zs, float* __restrict__ z2, int n) {
    int r = (blockIdx.x * 256 + threadIdx.x) >> 6;
    int l = threadIdx.x & 63;
    if (r >= n) return;
    float2 v = *(const float2*)(h + (size_t)r * D + l * 2);
    float4 cs = *(const float4*)(Cs + l * 4);
    float4 c2 = *(const float4*)(C2 + l * 4);
    float s0 = v.x * cs.x + v.y * cs.z;
    float s1 = v.x * cs.y + v.y * cs.w;
    float t0 = v.x * c2.x + v.y * c2.z;
    float t1 = v.x * c2.y + v.y * c2.w;
    #pragma unroll
    for (int off = 32; off > 0; off >>= 1) {
        s0 += __shfl_down(s0, off);
        s1 += __shfl_down(s1, off);
        t0 += __shfl_down(t0, off);
        t1 += __shfl_down(t1, off);
    }
    if (l == 0) {
        zs[(size_t)r * 2] = s0; zs[(size_t)r * 2 + 1] = s1;
        z2[(size_t)r * 2] = t0; z2[(size_t)r * 2 + 1] = t1;
    }
}

// ---------------- final: out[r] = zs[r] + gath1(za)/deg1 + gath2(z2)/deg2 + bconst
// 8 lanes per row; lanes stride the edge lists (independent 8B loads).
__global__ __launch_bounds__(256) void final_out_kernel(
        const float* __restrict__ zs, const float* __restrict__ za,
        const float* __restrict__ z2,
        const int* __restrict__ rp1, const int2* __restrict__ cw1,
        const int* __restrict__ rp2, const int2* __restrict__ cw2,
        const float* __restrict__ bconst, float* __restrict__ out, int n) {
    int r = (blockIdx.x * 256 + threadIdx.x) >> 3;
    int l = threadIdx.x & 7;
    if (r >= n) return;
    int s0 = rp1[r], s1 = rp1[r + 1];
    float q0 = 0.f, q1 = 0.f;
    for (int j = s0 + l; j < s1; j += 8) {
        int2 e = cw1[j];
        float w = __int_as_float(e.y);
        float2 v = *(const float2*)(za + (size_t)e.x * 2);
        q0 += w * v.x; q1 += w * v.y;
    }
    float inv1 = 1.0f / (float)max(s1 - s0, 1);
    float p0 = q0 * inv1, p1 = q1 * inv1;
    s0 = rp2[r]; s1 = rp2[r + 1];
    q0 = 0.f; q1 = 0.f;
    for (int j = s0 + l; j < s1; j += 8) {
        int2 e = cw2[j];
        float w = __int_as_float(e.y);
        float2 v = *(const float2*)(z2 + (size_t)e.x * 2);
        q0 += w * v.x; q1 += w * v.y;
    }
    float inv2 = 1.0f / (float)max(s1 - s0, 1);
    p0 += q0 * inv2; p1 += q1 * inv2;
    #pragma unroll
    for (int off = 1; off < 8; off <<= 1) {
        p0 += __shfl_xor(p0, off);
        p1 += __shfl_xor(p1, off);
    }
    if (l == 0) {
        float2 s = *(const float2*)(zs + (size_t)r * 2);
        out[(size_t)r * 2 + 0] = p0 + s.x + bconst[0];
        out[(size_t)r * 2 + 1] = p1 + s.y + bconst[1];
    }
}

extern "C" void kernel_launch(void* const* d_in, const int* in_sizes, int n_in,
                              void* d_out, int out_size, void* d_ws, size_t ws_size,
                              hipStream_t stream) {
    const float* x_app   = (const float*)d_in[0];
    const float* x_attr  = (const float*)d_in[1];
    const float* ew0     = (const float*)d_in[2];
    const float* ew1     = (const float*)d_in[3];
    const float* ew2     = (const float*)d_in[4];
    const float* Wself1  = (const float*)d_in[5];
    const float* Wneigh1 = (const float*)d_in[6];
    const float* b1      = (const float*)d_in[7];
    const float* Wself2  = (const float*)d_in[8];
    const float* Wneigh2 = (const float*)d_in[9];
    const float* b2      = (const float*)d_in[10];
    const float* Wc      = (const float*)d_in[11];
    const float* bc      = (const float*)d_in[12];
    const int* src0 = (const int*)d_in[13];
    const int* dst0 = (const int*)d_in[14];
    const int* src1 = (const int*)d_in[15];
    const int* dst1 = (const int*)d_in[16];
    const int* src2 = (const int*)d_in[17];
    const int* dst2 = (const int*)d_in[18];
    float* out = (float*)d_out;

    // ---- workspace layout (4-byte units; cw blocks start at even offsets) ----
    float* ws = (float*)d_ws;
    float* h_attr = ws;                                  // NATTR*D
    float* h_app  = h_attr + (size_t)NATTR * D;          // NAPP*D
    float* b1s    = h_app  + (size_t)NAPP * D;           // D
    float* b2s    = b1s + D;                             // D
    float* za     = b2s + D;                             // NATTR*2
    float* zsv    = za + (size_t)NATTR * 2;              // NAPP*2
    float* z2v    = zsv + (size_t)NAPP * 2;              // NAPP*2
    float* Cs     = z2v + (size_t)NAPP * 2;              // 256
    float* C1     = Cs + 256;                            // 256
    float* C2     = C1 + 256;                            // 256
    float* bconst = C2 + 256;                            // 4
    int* cur  = (int*)(bconst + 4);                      // SNB*SCHUNK
    int* cur0 = cur;
    int* cur1 = cur0 + NATTR;
    int* cur2 = cur1 + NAPP;
    int* rp0  = cur + SNB * SCHUNK;                      // NATTR+4
    int* rp1  = rp0 + NATTR + 4;                         // NAPP+4
    int* rp2  = rp1 + NAPP + 4;                          // NAPP+4
    int* bsum = rp2 + NAPP + 4;                          // 256
    int* boff = bsum + 256;                              // 256
    int2* cw0 = (int2*)(boff + 256);                     // NE int2
    int2* cw1 = cw0 + NE;                                // NE int2
    int2* cw2 = cw1 + NE;                                // NE int2
    short* PBh = (short*)(cw2 + NE);                     // 8*D*D shorts
    short* PBl = PBh + (size_t)8 * D * D;                // 8*D*D shorts

    const size_t MM = (size_t)D * D;
    short* W1self0_h = PBh + 0 * MM; short* W1self0_l = PBl + 0 * MM;
    short* W1ngh0_h  = PBh + 1 * MM; short* W1ngh0_l  = PBl + 1 * MM;
    short* W1s_h     = PBh + 2 * MM; short* W1s_l     = PBl + 2 * MM;
    short* W1ngh1_h  = PBh + 3 * MM; short* W1ngh1_l  = PBl + 3 * MM;
    short* W1ngh2_h  = PBh + 4 * MM; short* W1ngh2_l  = PBl + 4 * MM;

    hipMemsetAsync(cur, 0, (size_t)SNB * SCHUNK * sizeof(int), stream);

    pack_kernel<<<9, 256, 0, stream>>>(Wself1, Wneigh1, Wself2, Wneigh2,
                                       b1, b2, Wc, bc, PBh, PBl, b1s, b2s,
                                       Cs, C1, C2, bconst);

    // ---- CSR build ----
    hist3_kernel<<<3 * EGRID, 256, 0, stream>>>(dst0, dst1, dst2, cur0, cur1, cur2);
    scan_partial_kernel<<<SNB, 256, 0, stream>>>(cur, bsum);
    scan_offsets_kernel<<<1, 256, 0, stream>>>(bsum, boff, rp0, rp1, rp2);
    scan_final_kernel<<<SNB, 256, 0, stream>>>(cur, boff, rp0, rp1, rp2);
    scatter3_kernel<<<3 * EGRID, 256, 0, stream>>>(
        src0, dst0, ew0, cur0, cw0,
        src1, dst1, ew1, cur1, cw1,
        src2, dst2, ew2, cur2, cw2);

    // ---- layer 1 (fused gather + GEMM) ----
    fused_gemm_kernel<1><<<(NATTR + 63) / 64, 256, 0, stream>>>(
        x_attr, W1self0_h, W1self0_l,
        x_app, rp0, cw0, W1ngh0_h, W1ngh0_l,
        nullptr, nullptr, nullptr, nullptr, nullptr,
        b1, h_attr, NATTR, 1);
    fused_gemm_kernel<2><<<(NAPP + 63) / 64, 256, 0, stream>>>(
        x_app, W1s_h, W1s_l,
        x_attr, rp1, cw1, W1ngh1_h, W1ngh1_l,
        x_app,  rp2, cw2, W1ngh2_h, W1ngh2_l,
        b1s, h_app, NAPP, 1);

    // ---- layer 2 collapsed through the D=2 classifier (exact fp32) ----
    skinny1_kernel<<<((size_t)NATTR * 64 + 255) / 256, 256, 0, stream>>>(h_attr, C1, za, NATTR);
    skinny2_kernel<<<((size_t)NAPP * 64 + 255) / 256, 256, 0, stream>>>(h_app, Cs, C2, zsv, z2v, NAPP);
    final_out_kernel<<<((size_t)NAPP * 8 + 255) / 256, 256, 0, stream>>>(
        zsv, za, z2v, rp1, cw1, rp2, cw2, bconst, out, NAPP);
}